// Round 7
// baseline (191.680 us; speedup 1.0000x reference)
//
#include <hip/hip_runtime.h>

typedef short short4v __attribute__((ext_vector_type(4)));
typedef short short8 __attribute__((ext_vector_type(8)));
typedef float floatx4 __attribute__((ext_vector_type(4)));
typedef unsigned int uint;
typedef unsigned short ushort;

#define CH 512
#define NN 2048
#define DD 128
#define RSCALE 0.08838834764831845f  // 1/sqrt(128)

__device__ __forceinline__ float bf2f(ushort u) {
    union { uint i; float f; } v; v.i = ((uint)u) << 16; return v.f;
}
__device__ __forceinline__ ushort f2bf(float f) {
    union { float f; uint u; } v; v.f = f;
    uint u = v.u;
    return (ushort)((u + 0x7fffu + ((u >> 16) & 1u)) >> 16);
}

// ---------------------------------------------------------------------------
// K0a: zero lsum[8][2048]
// ---------------------------------------------------------------------------
__global__ void k0_zero(float* __restrict__ lsum) {
    lsum[blockIdx.x * 256 + threadIdx.x] = 0.0f;
}

// ---------------------------------------------------------------------------
// K0b: pre-convert weights to bf16. Wbf[256][512]: rows 0-127 = wqk, 128-255 = wv
// ---------------------------------------------------------------------------
__global__ __launch_bounds__(256) void k0_wconv(
    const float* __restrict__ wqk, const float* __restrict__ wv,
    ushort* __restrict__ Wbf)
{
    int gid = blockIdx.x * 256 + threadIdx.x;
    int base = gid * 4;
    const float* src = (base < 65536) ? (wqk + base) : (wv + base - 65536);
    float4 v = *(const float4*)src;
    short4v o;
    o[0] = (short)f2bf(v.x); o[1] = (short)f2bf(v.y);
    o[2] = (short)f2bf(v.z); o[3] = (short)f2bf(v.w);
    *(short4v*)&Wbf[base] = o;
}

// ---------------------------------------------------------------------------
// K1: projections, merged-d, bf16 weights. Block = [32 n][256 dstack].
// ---------------------------------------------------------------------------
__global__ __launch_bounds__(256) void k1_proj(
    const float* __restrict__ x,
    const ushort* __restrict__ Wbf,
    const float* __restrict__ bv,
    ushort* __restrict__ Q,
    ushort* __restrict__ V)
{
    const int nt = blockIdx.x;   // 0..63
    const int b  = blockIdx.y;   // 0..7
    const int n0 = nt * 32;
    const int t = threadIdx.x;
    const int lane = t & 63, w = t >> 6, l15 = lane & 15, quad = lane >> 4;

    __shared__ __attribute__((aligned(16))) ushort As[32 * 40];
    __shared__ __attribute__((aligned(16))) ushort Bs[256 * 40];

    floatx4 acc[2][4];
#pragma unroll
    for (int i = 0; i < 2; i++)
#pragma unroll
        for (int j = 0; j < 4; j++) acc[i][j] = (floatx4)(0.0f);

    const float* xb = x + b * (CH * NN) + n0;

    for (int c0 = 0; c0 < CH; c0 += 32) {
        {
            int n = t & 31, g = t >> 5;
            short4v v;
#pragma unroll
            for (int i = 0; i < 4; i++)
                v[i] = (short)f2bf(xb[(c0 + g * 4 + i) * NN + n]);
            *(short4v*)&As[n * 40 + g * 4] = v;
        }
#pragma unroll
        for (int rep = 0; rep < 16; rep++) {
            int idx = rep * 256 + t;
            int row = idx >> 4, cp = idx & 15;
            *(uint*)&Bs[row * 40 + cp * 2] = *(const uint*)&Wbf[row * CH + c0 + cp * 2];
        }
        __syncthreads();
        short8 a0 = *(short8*)&As[(l15) * 40 + quad * 8];
        short8 a1 = *(short8*)&As[(16 + l15) * 40 + quad * 8];
#pragma unroll
        for (int dt2 = 0; dt2 < 4; dt2++) {
            short8 bf = *(short8*)&Bs[(w * 64 + dt2 * 16 + l15) * 40 + quad * 8];
            acc[0][dt2] = __builtin_amdgcn_mfma_f32_16x16x32_bf16(a0, bf, acc[0][dt2], 0, 0, 0);
            acc[1][dt2] = __builtin_amdgcn_mfma_f32_16x16x32_bf16(a1, bf, acc[1][dt2], 0, 0, 0);
        }
        __syncthreads();
    }
#pragma unroll
    for (int ns = 0; ns < 2; ns++)
#pragma unroll
        for (int dt2 = 0; dt2 < 4; dt2++) {
            int ds_ = w * 64 + dt2 * 16 + l15;
#pragma unroll
            for (int r = 0; r < 4; r++) {
                int n = n0 + ns * 16 + quad * 4 + r;
                float val = acc[ns][dt2][r];
                if (ds_ < 128) {
                    Q[b * (NN * DD) + n * DD + ds_] = f2bf(val);
                } else {
                    int dv = ds_ - 128;
                    V[b * (NN * DD) + n * DD + dv] = f2bf(val + bv[dv]);
                }
            }
        }
}

// ---------------------------------------------------------------------------
// KL: l_n row sums only (round-5 k2_qqt with P-store removed).
// Block = 128(i) x 64(j) S-tile; atomicAdd partial row sums into lsum.
// ---------------------------------------------------------------------------
__global__ __launch_bounds__(256) void kl_sum(
    const ushort* __restrict__ Q,   // [B][N][D] bf16
    float* __restrict__ lsum)       // [B][N]
{
    const int it = blockIdx.x;   // 0..15
    const int jt = blockIdx.y;   // 0..31
    const int b  = blockIdx.z;
    const int i0 = it * 128, j0 = jt * 64;
    const int t = threadIdx.x;
    const int lane = t & 63, w = t >> 6, l15 = lane & 15, quad = lane >> 4;
    const int wi = (w >> 1) * 64, wj = (w & 1) * 32;

    __shared__ __attribute__((aligned(16))) ushort Qi[128 * 136];
    __shared__ __attribute__((aligned(16))) ushort Qj[64 * 136];

    const ushort* Qb = Q + b * (NN * DD);

#pragma unroll
    for (int rep = 0; rep < 8; rep++) {
        int idx = rep * 256 + t;
        int row = idx >> 4, g = idx & 15;
        *(short8*)&Qi[row * 136 + g * 8] = *(const short8*)&Qb[(i0 + row) * DD + g * 8];
    }
#pragma unroll
    for (int rep = 0; rep < 4; rep++) {
        int idx = rep * 256 + t;
        int row = idx >> 4, g = idx & 15;
        *(short8*)&Qj[row * 136 + g * 8] = *(const short8*)&Qb[(j0 + row) * DD + g * 8];
    }
    __syncthreads();

    floatx4 acc[4][2];
#pragma unroll
    for (int i = 0; i < 4; i++)
#pragma unroll
        for (int j = 0; j < 2; j++) acc[i][j] = (floatx4)(0.0f);

#pragma unroll
    for (int kd = 0; kd < 4; kd++) {
        short8 afr[4], bfr[2];
#pragma unroll
        for (int nt = 0; nt < 4; nt++)
            afr[nt] = *(short8*)&Qi[(wi + nt * 16 + l15) * 136 + kd * 32 + quad * 8];
#pragma unroll
        for (int mt = 0; mt < 2; mt++)
            bfr[mt] = *(short8*)&Qj[(wj + mt * 16 + l15) * 136 + kd * 32 + quad * 8];
#pragma unroll
        for (int nt = 0; nt < 4; nt++)
#pragma unroll
            for (int mt = 0; mt < 2; mt++)
                acc[nt][mt] = __builtin_amdgcn_mfma_f32_16x16x32_bf16(afr[nt], bfr[mt], acc[nt][mt], 0, 0, 0);
    }

#pragma unroll
    for (int nt = 0; nt < 4; nt++) {
        float rs[4] = {0.f, 0.f, 0.f, 0.f};
#pragma unroll
        for (int mt = 0; mt < 2; mt++)
#pragma unroll
            for (int r = 0; r < 4; r++)
                rs[r] += __expf(acc[nt][mt][r] * RSCALE);
#pragma unroll
        for (int r = 0; r < 4; r++) {
            float s = rs[r];
            s += __shfl_xor(s, 1);
            s += __shfl_xor(s, 2);
            s += __shfl_xor(s, 4);
            s += __shfl_xor(s, 8);
            if (l15 == 0)
                atomicAdd(&lsum[b * NN + i0 + wi + nt * 16 + quad * 4 + r], s);
        }
    }
}

// ---------------------------------------------------------------------------
// K2c: VT[b][d][n] = V[b][n][d] / lsum[b][n]  (LDS transpose, round-5 proven)
// ---------------------------------------------------------------------------
__global__ __launch_bounds__(256) void k2_scale_t(
    const ushort* __restrict__ V,
    const float* __restrict__ lsum,
    ushort* __restrict__ VT)
{
    const int nt = blockIdx.x;  // 0..31
    const int b = blockIdx.y;
    const int n0 = nt * 64;
    const int t = threadIdx.x;

    __shared__ __attribute__((aligned(16))) ushort Vt[64 * 132];

    const ushort* Vb = V + b * (NN * DD);
#pragma unroll
    for (int rep = 0; rep < 16; rep++) {
        int idx = rep * 256 + t;
        int row = idx >> 6, dp = idx & 63;
        *(uint*)&Vt[row * 132 + dp * 2] = *(const uint*)&Vb[(n0 + row) * DD + dp * 2];
    }
    __syncthreads();
#pragma unroll
    for (int rep = 0; rep < 16; rep++) {
        int idx = rep * 256 + t;
        int d = idx >> 5, col2 = idx & 31;
        int n = n0 + col2 * 2;
        float l0 = 1.0f / lsum[b * NN + n], l1 = 1.0f / lsum[b * NN + n + 1];
        float v0 = bf2f(Vt[(col2 * 2) * 132 + d]) * l0;
        float v1 = bf2f(Vt[(col2 * 2 + 1) * 132 + d]) * l1;
        uint pack = (uint)f2bf(v0) | ((uint)f2bf(v1) << 16);
        *(uint*)&VT[(size_t)b * DD * NN + (size_t)d * NN + n] = pack;
    }
}

// ---------------------------------------------------------------------------
// K3: FUSED attention, V pre-normalized. out[d][m] = sum_n VT'[d][n]*p[m][n].
// Block owns m-tile 32 (all 128 d); streams n in 64-chunks; P in LDS only.
// ---------------------------------------------------------------------------
__global__ __launch_bounds__(256) void k_fused(
    const ushort* __restrict__ Q,   // [B][N][D] bf16
    const ushort* __restrict__ VT,  // [B][D][N] bf16 (V/l_n, transposed)
    float* __restrict__ out)        // [B][D][N] fp32
{
    const int mt = blockIdx.x;  // 0..63
    const int b = blockIdx.y;
    const int m0 = mt * 32;
    const int t = threadIdx.x;
    const int lane = t & 63, w = t >> 6, l15 = lane & 15, quad = lane >> 4;

    __shared__ __attribute__((aligned(16))) ushort Qm[32 * 136];
    __shared__ __attribute__((aligned(16))) ushort Qn[64 * 136];
    __shared__ __attribute__((aligned(16))) ushort Vs[128 * 72];
    __shared__ __attribute__((aligned(16))) ushort Ps[32 * 68];

    const ushort* Qb = Q + b * (NN * DD);
    const ushort* VTb = VT + (size_t)b * DD * NN;

    // stage Qm (32 rows x 128 d)
#pragma unroll
    for (int rep = 0; rep < 2; rep++) {
        int idx = rep * 256 + t;
        int row = idx >> 4, g = idx & 15;
        *(short8*)&Qm[row * 136 + g * 8] = *(const short8*)&Qb[(m0 + row) * DD + g * 8];
    }
    __syncthreads();

    // preload S A-frags: A[m=l15][k=d]
    short8 qm[2][4];
#pragma unroll
    for (int ms = 0; ms < 2; ms++)
#pragma unroll
        for (int kd = 0; kd < 4; kd++)
            qm[ms][kd] = *(short8*)&Qm[(ms * 16 + l15) * 136 + kd * 32 + quad * 8];

    floatx4 acc[2][2];
#pragma unroll
    for (int i = 0; i < 2; i++)
#pragma unroll
        for (int j = 0; j < 2; j++) acc[i][j] = (floatx4)(0.0f);

    for (int n0c = 0; n0c < NN; n0c += 64) {
        __syncthreads();  // prior chunk's readers done before restaging
        // stage Qn: [64 n][128 d]
#pragma unroll
        for (int rep = 0; rep < 4; rep++) {
            int idx = rep * 256 + t;
            int row = idx >> 4, g = idx & 15;
            *(short8*)&Qn[row * 136 + g * 8] = *(const short8*)&Qb[(n0c + row) * DD + g * 8];
        }
        // stage Vs: [128 d][64 n] from VT rows (contiguous)
#pragma unroll
        for (int rep = 0; rep < 4; rep++) {
            int idx = rep * 256 + t;
            int d = idx >> 3, g = idx & 7;
            *(short8*)&Vs[d * 72 + g * 8] = *(const short8*)&VTb[(size_t)d * NN + n0c + g * 8];
        }
        __syncthreads();

        // S stage: wave w computes S[m 0..32][n-band w*16..w*16+16]
#pragma unroll
        for (int ms = 0; ms < 2; ms++) {
            floatx4 s = (floatx4)(0.0f);
#pragma unroll
            for (int kd = 0; kd < 4; kd++) {
                short8 bq = *(short8*)&Qn[(w * 16 + l15) * 136 + kd * 32 + quad * 8];
                s = __builtin_amdgcn_mfma_f32_16x16x32_bf16(qm[ms][kd], bq, s, 0, 0, 0);
            }
#pragma unroll
            for (int r = 0; r < 4; r++) {
                float p = __expf(s[r] * RSCALE);
                // row m = ms*16 + quad*4 + r, col n = w*16 + l15
                Ps[(ms * 16 + quad * 4 + r) * 68 + w * 16 + l15] = f2bf(p);
            }
        }
        __syncthreads();

        // PV stage: wave w owns d-band w*32; A = Vs rows d, B = Ps (k=n, col=m)
#pragma unroll
        for (int kn = 0; kn < 2; kn++) {
            short8 va0 = *(short8*)&Vs[(w * 32 + l15) * 72 + kn * 32 + quad * 8];
            short8 va1 = *(short8*)&Vs[(w * 32 + 16 + l15) * 72 + kn * 32 + quad * 8];
            short8 pb0 = *(short8*)&Ps[(l15) * 68 + kn * 32 + quad * 8];
            short8 pb1 = *(short8*)&Ps[(16 + l15) * 68 + kn * 32 + quad * 8];
            acc[0][0] = __builtin_amdgcn_mfma_f32_16x16x32_bf16(va0, pb0, acc[0][0], 0, 0, 0);
            acc[0][1] = __builtin_amdgcn_mfma_f32_16x16x32_bf16(va0, pb1, acc[0][1], 0, 0, 0);
            acc[1][0] = __builtin_amdgcn_mfma_f32_16x16x32_bf16(va1, pb0, acc[1][0], 0, 0, 0);
            acc[1][1] = __builtin_amdgcn_mfma_f32_16x16x32_bf16(va1, pb1, acc[1][1], 0, 0, 0);
        }
    }

    // store out[d][m0+m]; C-frag: col = m = mc*16+l15, row = d
    float* ob = out + (size_t)b * DD * NN;
#pragma unroll
    for (int dsub = 0; dsub < 2; dsub++)
#pragma unroll
        for (int r = 0; r < 4; r++) {
            int d = w * 32 + dsub * 16 + quad * 4 + r;
            ob[(size_t)d * NN + m0 + l15]      = acc[dsub][0][r];
            ob[(size_t)d * NN + m0 + 16 + l15] = acc[dsub][1][r];
        }
}

// ---------------------------------------------------------------------------
// Fallback path (small ws) — round-3 proven kernels
// ---------------------------------------------------------------------------
__global__ __launch_bounds__(256) void k1_fb(
    const float* __restrict__ x, const float* __restrict__ wqk,
    const float* __restrict__ wv, const float* __restrict__ bv,
    ushort* __restrict__ Q, ushort* __restrict__ V)
{
    const int nt = blockIdx.x;
    const int b  = blockIdx.y;
    const int n0 = nt * 32;
    const int t = threadIdx.x;
    const int lane = t & 63, w = t >> 6, l15 = lane & 15, quad = lane >> 4;

    __shared__ __attribute__((aligned(16))) ushort As[32 * 40];
    __shared__ __attribute__((aligned(16))) ushort Bs[256 * 40];

    floatx4 acc[2][4];
#pragma unroll
    for (int i = 0; i < 2; i++)
#pragma unroll
        for (int j = 0; j < 4; j++) acc[i][j] = (floatx4)(0.0f);

    const float* xb = x + b * (CH * NN) + n0;

    for (int c0 = 0; c0 < CH; c0 += 32) {
        {
            int n = t & 31, g = t >> 5;
            short4v v;
#pragma unroll
            for (int i = 0; i < 4; i++)
                v[i] = (short)f2bf(xb[(c0 + g * 4 + i) * NN + n]);
            *(short4v*)&As[n * 40 + g * 4] = v;
        }
#pragma unroll
        for (int rep = 0; rep < 16; rep++) {
            int idx = rep * 256 + t;
            int row = idx >> 4, cp = idx & 15;
            const float* wf = (row < 128) ? (wqk + row * CH) : (wv + (row - 128) * CH);
            uint pack = (uint)f2bf(wf[c0 + cp * 2]) | ((uint)f2bf(wf[c0 + cp * 2 + 1]) << 16);
            *(uint*)&Bs[row * 40 + cp * 2] = pack;
        }
        __syncthreads();
        short8 a0 = *(short8*)&As[(l15) * 40 + quad * 8];
        short8 a1 = *(short8*)&As[(16 + l15) * 40 + quad * 8];
#pragma unroll
        for (int dt2 = 0; dt2 < 4; dt2++) {
            short8 bf = *(short8*)&Bs[(w * 64 + dt2 * 16 + l15) * 40 + quad * 8];
            acc[0][dt2] = __builtin_amdgcn_mfma_f32_16x16x32_bf16(a0, bf, acc[0][dt2], 0, 0, 0);
            acc[1][dt2] = __builtin_amdgcn_mfma_f32_16x16x32_bf16(a1, bf, acc[1][dt2], 0, 0, 0);
        }
        __syncthreads();
    }
#pragma unroll
    for (int ns = 0; ns < 2; ns++)
#pragma unroll
        for (int dt2 = 0; dt2 < 4; dt2++) {
            int ds_ = w * 64 + dt2 * 16 + l15;
#pragma unroll
            for (int r = 0; r < 4; r++) {
                int n = n0 + ns * 16 + quad * 4 + r;
                float val = acc[ns][dt2][r];
                if (ds_ < 128) {
                    Q[b * (NN * DD) + n * DD + ds_] = f2bf(val);
                } else {
                    int dv = ds_ - 128;
                    V[b * (NN * DD) + n * DD + dv] = f2bf(val + bv[dv]);
                }
            }
        }
}

__global__ __launch_bounds__(256) void k2_norm(
    const ushort* __restrict__ Q, ushort* __restrict__ V)
{
    const int ntile = blockIdx.x;
    const int b = blockIdx.y;
    const int n0 = ntile * 64;
    const int t = threadIdx.x;
    const int lane = t & 63, w = t >> 6, l15 = lane & 15, quad = lane >> 4;

    __shared__ __attribute__((aligned(16))) ushort Qs[64 * 136];
    __shared__ __attribute__((aligned(16))) ushort Qm2[64 * 136];

    const ushort* Qb = Q + b * (NN * DD);

#pragma unroll
    for (int rep = 0; rep < 16; rep++) {
        int idx = rep * 256 + t;
        int row = idx >> 6, dp = idx & 63;
        *(uint*)&Qs[row * 136 + dp * 2] = *(const uint*)&Qb[(n0 + row) * DD + dp * 2];
    }
    __syncthreads();

    short8 afr[4];
#pragma unroll
    for (int kd = 0; kd < 4; kd++)
        afr[kd] = *(short8*)&Qs[(w * 16 + l15) * 136 + kd * 32 + quad * 8];

    float sums[4] = {0.f, 0.f, 0.f, 0.f};

    for (int m0 = 0; m0 < NN; m0 += 64) {
#pragma unroll
        for (int rep = 0; rep < 16; rep++) {
            int idx = rep * 256 + t;
            int row = idx >> 6, dp = idx & 63;
            *(uint*)&Qm2[row * 136 + dp * 2] = *(const uint*)&Qb[(m0 + row) * DD + dp * 2];
        }
        __syncthreads();
#pragma unroll
        for (int ct = 0; ct < 4; ct++) {
            floatx4 s = (floatx4)(0.0f);
#pragma unroll
            for (int kd = 0; kd < 4; kd++) {
                short8 bf = *(short8*)&Qm2[(ct * 16 + l15) * 136 + kd * 32 + quad * 8];
                s = __builtin_amdgcn_mfma_f32_16x16x32_bf16(afr[kd], bf, s, 0, 0, 0);
            }
#pragma unroll
            for (int r = 0; r < 4; r++)
                sums[r] += __expf(s[r] * RSCALE);
        }
        __syncthreads();
    }

#pragma unroll
    for (int r = 0; r < 4; r++) {
        float s = sums[r];
        s += __shfl_xor(s, 1);
        s += __shfl_xor(s, 2);
        s += __shfl_xor(s, 4);
        s += __shfl_xor(s, 8);
        sums[r] = s;
    }

    ushort* Vb = V + b * (NN * DD);
#pragma unroll
    for (int r = 0; r < 4; r++) {
        int n = n0 + w * 16 + quad * 4 + r;
        float inv = 1.0f / sums[r];
        short8 vv = *(short8*)&Vb[n * DD + l15 * 8];
        short8 o;
#pragma unroll
        for (int i = 0; i < 8; i++)
            o[i] = (short)f2bf(bf2f((ushort)vv[i]) * inv);
        *(short8*)&Vb[n * DD + l15 * 8] = o;
    }
}

__global__ __launch_bounds__(256) void k3_attn(
    const ushort* __restrict__ Q, const ushort* __restrict__ Vp,
    float* __restrict__ out)
{
    const int mtile = blockIdx.x;
    const int b = blockIdx.y;
    const int m0 = mtile * 64;
    const int t = threadIdx.x;
    const int lane = t & 63, w = t >> 6, l15 = lane & 15, quad = lane >> 4;

    __shared__ __attribute__((aligned(16))) ushort Qs[64 * 136];
    __shared__ __attribute__((aligned(16))) ushort Qn2[32 * 136];
    __shared__ __attribute__((aligned(16))) ushort Vs2[128 * 40];
    __shared__ __attribute__((aligned(16))) ushort Ps2[64 * 40];

    const ushort* Qb = Q + b * (NN * DD);
    const ushort* Vpb = Vp + b * (NN * DD);

#pragma unroll
    for (int rep = 0; rep < 16; rep++) {
        int idx = rep * 256 + t;
        int row = idx >> 6, dp = idx & 63;
        *(uint*)&Qs[row * 136 + dp * 2] = *(const uint*)&Qb[(m0 + row) * DD + dp * 2];
    }
    __syncthreads();

    short8 afr[4];
#pragma unroll
    for (int kd = 0; kd < 4; kd++)
        afr[kd] = *(short8*)&Qs[(w * 16 + l15) * 136 + kd * 32 + quad * 8];

    floatx4 acc[2][4];
#pragma unroll
    for (int s = 0; s < 2; s++)
#pragma unroll
        for (int mt = 0; mt < 4; mt++) acc[s][mt] = (floatx4)(0.0f);

    for (int n0c = 0; n0c < NN; n0c += 32) {
#pragma unroll
        for (int rep = 0; rep < 8; rep++) {
            int idx = rep * 256 + t;
            int row = idx >> 6, dp = idx & 63;
            *(uint*)&Qn2[row * 136 + dp * 2] = *(const uint*)&Qb[(n0c + row) * DD + dp * 2];
        }
#pragma unroll
        for (int rep = 0; rep < 8; rep++) {
            int idx = rep * 256 + t;
            int np = idx >> 7, d = idx & 127;
            uint v0 = Vpb[(n0c + np * 2) * DD + d];
            uint v1 = Vpb[(n0c + np * 2 + 1) * DD + d];
            *(uint*)&Vs2[d * 40 + np * 2] = v0 | (v1 << 16);
        }
        __syncthreads();

#pragma unroll
        for (int nt2 = 0; nt2 < 2; nt2++) {
            floatx4 s = (floatx4)(0.0f);
#pragma unroll
            for (int kd = 0; kd < 4; kd++) {
                short8 bf = *(short8*)&Qn2[(nt2 * 16 + l15) * 136 + kd * 32 + quad * 8];
                s = __builtin_amdgcn_mfma_f32_16x16x32_bf16(afr[kd], bf, s, 0, 0, 0);
            }
#pragma unroll
            for (int r = 0; r < 4; r++) {
                float p = __expf(s[r] * RSCALE);
                Ps2[(w * 16 + quad * 4 + r) * 40 + nt2 * 16 + l15] = f2bf(p);
            }
        }
        __syncthreads();

        short8 pb[4];
#pragma unroll
        for (int mt = 0; mt < 4; mt++)
            pb[mt] = *(short8*)&Ps2[(mt * 16 + l15) * 40 + quad * 8];
#pragma unroll
        for (int sub = 0; sub < 2; sub++) {
            short8 va = *(short8*)&Vs2[(w * 32 + sub * 16 + l15) * 40 + quad * 8];
#pragma unroll
            for (int mt = 0; mt < 4; mt++)
                acc[sub][mt] = __builtin_amdgcn_mfma_f32_16x16x32_bf16(va, pb[mt], acc[sub][mt], 0, 0, 0);
        }
        __syncthreads();
    }

    float* ob = out + (size_t)b * DD * NN;
#pragma unroll
    for (int sub = 0; sub < 2; sub++)
#pragma unroll
        for (int mt = 0; mt < 4; mt++)
#pragma unroll
            for (int r = 0; r < 4; r++) {
                int d = w * 32 + sub * 16 + quad * 4 + r;
                int m = m0 + mt * 16 + l15;
                ob[(size_t)d * NN + m] = acc[sub][mt][r];
            }
}

extern "C" void kernel_launch(void* const* d_in, const int* in_sizes, int n_in,
                              void* d_out, int out_size, void* d_ws, size_t ws_size,
                              hipStream_t stream) {
    const float* x   = (const float*)d_in[0];
    const float* wqk = (const float*)d_in[1];
    const float* wv  = (const float*)d_in[2];
    const float* bv  = (const float*)d_in[3];
    float* out = (float*)d_out;

    // ws: Q [0,4M) | V [4M,8M) | Wbf @8M (256K) | lsum @8M+256K (64K) | VT @12M (4M)
    ushort* Q = (ushort*)d_ws;
    ushort* V = (ushort*)((char*)d_ws + (4u << 20));

    if (ws_size >= (size_t)16 * 1024 * 1024) {
        ushort* Wbf  = (ushort*)((char*)d_ws + (8u << 20));
        float*  lsum = (float*)((char*)d_ws + (8u << 20) + (256u << 10));
        ushort* VT   = (ushort*)((char*)d_ws + (12u << 20));

        k0_zero<<<64, 256, 0, stream>>>(lsum);
        k0_wconv<<<128, 256, 0, stream>>>(wqk, wv, Wbf);
        k1_proj<<<dim3(64, 8), 256, 0, stream>>>(x, Wbf, bv, Q, V);
        kl_sum<<<dim3(16, 32, 8), 256, 0, stream>>>(Q, lsum);
        k2_scale_t<<<dim3(32, 8), 256, 0, stream>>>(V, lsum, VT);
        k_fused<<<dim3(64, 8), 256, 0, stream>>>(Q, VT, out);
    } else {
        k1_fb<<<dim3(64, 8), 256, 0, stream>>>(x, wqk, wv, bv, Q, V);
        k2_norm<<<dim3(32, 8), 256, 0, stream>>>(Q, V);
        k3_attn<<<dim3(32, 8), 256, 0, stream>>>(Q, V, out);
    }
}

// Round 8
// 168.146 us; speedup vs baseline: 1.1400x; 1.1400x over previous
//
#include <hip/hip_runtime.h>

typedef short short4v __attribute__((ext_vector_type(4)));
typedef short short8 __attribute__((ext_vector_type(8)));
typedef float floatx4 __attribute__((ext_vector_type(4)));
typedef unsigned int uint;
typedef unsigned short ushort;

#define CH 512
#define NN 2048
#define DD 128
#define RSCALE 0.08838834764831845f  // 1/sqrt(128)

__device__ __forceinline__ float bf2f(ushort u) {
    union { uint i; float f; } v; v.i = ((uint)u) << 16; return v.f;
}
__device__ __forceinline__ ushort f2bf(float f) {
    union { float f; uint u; } v; v.f = f;
    uint u = v.u;
    return (ushort)((u + 0x7fffu + ((u >> 16) & 1u)) >> 16);
}

// ---------------------------------------------------------------------------
// K0: weights -> bf16 AND zero lsum (merged; one launch)
// ---------------------------------------------------------------------------
__global__ __launch_bounds__(256) void k0_prep(
    const float* __restrict__ wqk, const float* __restrict__ wv,
    ushort* __restrict__ Wbf, float* __restrict__ lsum)
{
    int gid = blockIdx.x * 256 + threadIdx.x;  // 32768 threads
    int base = gid * 4;
    const float* src = (base < 65536) ? (wqk + base) : (wv + base - 65536);
    float4 v = *(const float4*)src;
    short4v o;
    o[0] = (short)f2bf(v.x); o[1] = (short)f2bf(v.y);
    o[2] = (short)f2bf(v.z); o[3] = (short)f2bf(v.w);
    *(short4v*)&Wbf[base] = o;
    if (gid < 16384) lsum[gid] = 0.0f;
}

// ---------------------------------------------------------------------------
// K1: projections, merged-d, bf16 weights. Block = [32 n][256 dstack].
// ---------------------------------------------------------------------------
__global__ __launch_bounds__(256) void k1_proj(
    const float* __restrict__ x,
    const ushort* __restrict__ Wbf,
    const float* __restrict__ bv,
    ushort* __restrict__ Q,
    ushort* __restrict__ V)
{
    const int nt = blockIdx.x;   // 0..63
    const int b  = blockIdx.y;   // 0..7
    const int n0 = nt * 32;
    const int t = threadIdx.x;
    const int lane = t & 63, w = t >> 6, l15 = lane & 15, quad = lane >> 4;

    __shared__ __attribute__((aligned(16))) ushort As[32 * 40];
    __shared__ __attribute__((aligned(16))) ushort Bs[256 * 40];

    floatx4 acc[2][4];
#pragma unroll
    for (int i = 0; i < 2; i++)
#pragma unroll
        for (int j = 0; j < 4; j++) acc[i][j] = (floatx4)(0.0f);

    const float* xb = x + b * (CH * NN) + n0;

    for (int c0 = 0; c0 < CH; c0 += 32) {
        {
            int n = t & 31, g = t >> 5;
            short4v v;
#pragma unroll
            for (int i = 0; i < 4; i++)
                v[i] = (short)f2bf(xb[(c0 + g * 4 + i) * NN + n]);
            *(short4v*)&As[n * 40 + g * 4] = v;
        }
#pragma unroll
        for (int rep = 0; rep < 16; rep++) {
            int idx = rep * 256 + t;
            int row = idx >> 4, cp = idx & 15;
            *(uint*)&Bs[row * 40 + cp * 2] = *(const uint*)&Wbf[row * CH + c0 + cp * 2];
        }
        __syncthreads();
        short8 a0 = *(short8*)&As[(l15) * 40 + quad * 8];
        short8 a1 = *(short8*)&As[(16 + l15) * 40 + quad * 8];
#pragma unroll
        for (int dt2 = 0; dt2 < 4; dt2++) {
            short8 bf = *(short8*)&Bs[(w * 64 + dt2 * 16 + l15) * 40 + quad * 8];
            acc[0][dt2] = __builtin_amdgcn_mfma_f32_16x16x32_bf16(a0, bf, acc[0][dt2], 0, 0, 0);
            acc[1][dt2] = __builtin_amdgcn_mfma_f32_16x16x32_bf16(a1, bf, acc[1][dt2], 0, 0, 0);
        }
        __syncthreads();
    }
#pragma unroll
    for (int ns = 0; ns < 2; ns++)
#pragma unroll
        for (int dt2 = 0; dt2 < 4; dt2++) {
            int ds_ = w * 64 + dt2 * 16 + l15;
#pragma unroll
            for (int r = 0; r < 4; r++) {
                int n = n0 + ns * 16 + quad * 4 + r;
                float val = acc[ns][dt2][r];
                if (ds_ < 128) {
                    Q[b * (NN * DD) + n * DD + ds_] = f2bf(val);
                } else {
                    int dv = ds_ - 128;
                    V[b * (NN * DD) + n * DD + dv] = f2bf(val + bv[dv]);
                }
            }
        }
}

// ---------------------------------------------------------------------------
// KL: l_n row sums via SYMMETRIC 128x128 S-tiles; only jt >= it computed.
// Off-diagonal tiles contribute row sums (i-band) AND column sums (j-band).
// ---------------------------------------------------------------------------
__global__ __launch_bounds__(256) void kl_sum(
    const ushort* __restrict__ Q,   // [B][N][D] bf16
    float* __restrict__ lsum)       // [B][N]
{
    int pid = blockIdx.x;  // 0..135
    const int b = blockIdx.y;
    int it = 0;
    while (pid >= (16 - it)) { pid -= (16 - it); it++; }
    const int jt = it + pid;
    const int i0 = it * 128, j0 = jt * 128;
    const int t = threadIdx.x;
    const int lane = t & 63, w = t >> 6, l15 = lane & 15, quad = lane >> 4;
    const int wi = (w >> 1) * 64, wj = (w & 1) * 64;

    __shared__ __attribute__((aligned(16))) ushort Qi[128 * 136];
    __shared__ __attribute__((aligned(16))) ushort Qj[128 * 136];

    const ushort* Qb = Q + b * (NN * DD);

#pragma unroll
    for (int rep = 0; rep < 8; rep++) {
        int idx = rep * 256 + t;
        int row = idx >> 4, g = idx & 15;
        *(short8*)&Qi[row * 136 + g * 8] = *(const short8*)&Qb[(i0 + row) * DD + g * 8];
        *(short8*)&Qj[row * 136 + g * 8] = *(const short8*)&Qb[(j0 + row) * DD + g * 8];
    }
    __syncthreads();

    floatx4 acc[4][4];
#pragma unroll
    for (int i = 0; i < 4; i++)
#pragma unroll
        for (int j = 0; j < 4; j++) acc[i][j] = (floatx4)(0.0f);

#pragma unroll
    for (int kd = 0; kd < 4; kd++) {
        short8 afr[4], bfr[4];
#pragma unroll
        for (int nt = 0; nt < 4; nt++)
            afr[nt] = *(short8*)&Qi[(wi + nt * 16 + l15) * 136 + kd * 32 + quad * 8];
#pragma unroll
        for (int mt = 0; mt < 4; mt++)
            bfr[mt] = *(short8*)&Qj[(wj + mt * 16 + l15) * 136 + kd * 32 + quad * 8];
#pragma unroll
        for (int nt = 0; nt < 4; nt++)
#pragma unroll
            for (int mt = 0; mt < 4; mt++)
                acc[nt][mt] = __builtin_amdgcn_mfma_f32_16x16x32_bf16(afr[nt], bfr[mt], acc[nt][mt], 0, 0, 0);
    }

    // epilogue: p = exp(S/sqrt(D)); row sums (i) + column sums (j)
    float cs[4] = {0.f, 0.f, 0.f, 0.f};
#pragma unroll
    for (int nt = 0; nt < 4; nt++) {
        float rs[4] = {0.f, 0.f, 0.f, 0.f};
#pragma unroll
        for (int mt = 0; mt < 4; mt++)
#pragma unroll
            for (int r = 0; r < 4; r++) {
                float p = __expf(acc[nt][mt][r] * RSCALE);
                rs[r] += p;
                cs[mt] += p;
            }
#pragma unroll
        for (int r = 0; r < 4; r++) {
            float s = rs[r];
            s += __shfl_xor(s, 1);
            s += __shfl_xor(s, 2);
            s += __shfl_xor(s, 4);
            s += __shfl_xor(s, 8);
            if (l15 == 0)
                atomicAdd(&lsum[b * NN + i0 + wi + nt * 16 + quad * 4 + r], s);
        }
    }
    if (it != jt) {
#pragma unroll
        for (int mt = 0; mt < 4; mt++) {
            float s = cs[mt];
            s += __shfl_xor(s, 16);
            s += __shfl_xor(s, 32);
            if (lane < 16)
                atomicAdd(&lsum[b * NN + j0 + wj + mt * 16 + l15], s);
        }
    }
}

// ---------------------------------------------------------------------------
// K2c: VT[b][d][n] = V[b][n][d] / lsum[b][n]  (LDS transpose)
// ---------------------------------------------------------------------------
__global__ __launch_bounds__(256) void k2_scale_t(
    const ushort* __restrict__ V,
    const float* __restrict__ lsum,
    ushort* __restrict__ VT)
{
    const int nt = blockIdx.x;  // 0..31
    const int b = blockIdx.y;
    const int n0 = nt * 64;
    const int t = threadIdx.x;

    __shared__ __attribute__((aligned(16))) ushort Vt[64 * 132];

    const ushort* Vb = V + b * (NN * DD);
#pragma unroll
    for (int rep = 0; rep < 16; rep++) {
        int idx = rep * 256 + t;
        int row = idx >> 6, dp = idx & 63;
        *(uint*)&Vt[row * 132 + dp * 2] = *(const uint*)&Vb[(n0 + row) * DD + dp * 2];
    }
    __syncthreads();
#pragma unroll
    for (int rep = 0; rep < 16; rep++) {
        int idx = rep * 256 + t;
        int d = idx >> 5, col2 = idx & 31;
        int n = n0 + col2 * 2;
        float l0 = 1.0f / lsum[b * NN + n], l1 = 1.0f / lsum[b * NN + n + 1];
        float v0 = bf2f(Vt[(col2 * 2) * 132 + d]) * l0;
        float v1 = bf2f(Vt[(col2 * 2 + 1) * 132 + d]) * l1;
        uint pack = (uint)f2bf(v0) | ((uint)f2bf(v1) << 16);
        *(uint*)&VT[(size_t)b * DD * NN + (size_t)d * NN + n] = pack;
    }
}

// ---------------------------------------------------------------------------
// K3: FUSED attention, m-tile 64. out[d][m] = sum_n VT'[d][n]*exp(S[m][n]).
// Block owns 64 m (all 128 d); streams n in 64-chunks; P in LDS only.
// 32 MFMA/wave per 32 KB staged chunk (2x round-7 density).
// ---------------------------------------------------------------------------
__global__ __launch_bounds__(256) void k_fused(
    const ushort* __restrict__ Q,   // [B][N][D] bf16
    const ushort* __restrict__ VT,  // [B][D][N] bf16 (V/l_n, transposed)
    float* __restrict__ out)        // [B][D][N] fp32
{
    const int mt = blockIdx.x;  // 0..31
    const int b = blockIdx.y;
    const int m0 = mt * 64;
    const int t = threadIdx.x;
    const int lane = t & 63, w = t >> 6, l15 = lane & 15, quad = lane >> 4;

    __shared__ __attribute__((aligned(16))) ushort Qm[64 * 136];
    __shared__ __attribute__((aligned(16))) ushort Qn[64 * 136];
    __shared__ __attribute__((aligned(16))) ushort Vs[128 * 72];
    __shared__ __attribute__((aligned(16))) ushort Ps[64 * 68];

    const ushort* Qb = Q + b * (NN * DD);
    const ushort* VTb = VT + (size_t)b * DD * NN;

    // stage Qm (64 rows x 128 d)
#pragma unroll
    for (int rep = 0; rep < 4; rep++) {
        int idx = rep * 256 + t;
        int row = idx >> 4, g = idx & 15;
        *(short8*)&Qm[row * 136 + g * 8] = *(const short8*)&Qb[(m0 + row) * DD + g * 8];
    }
    __syncthreads();

    // preload S A-frags: A[m = ms*16 + l15][k = d]
    short8 qm[4][4];
#pragma unroll
    for (int ms = 0; ms < 4; ms++)
#pragma unroll
        for (int kd = 0; kd < 4; kd++)
            qm[ms][kd] = *(short8*)&Qm[(ms * 16 + l15) * 136 + kd * 32 + quad * 8];

    floatx4 acc[2][4];
#pragma unroll
    for (int i = 0; i < 2; i++)
#pragma unroll
        for (int j = 0; j < 4; j++) acc[i][j] = (floatx4)(0.0f);

    for (int n0c = 0; n0c < NN; n0c += 64) {
        __syncthreads();  // prior chunk's readers done before restaging
        // stage Qn: [64 n][128 d]
#pragma unroll
        for (int rep = 0; rep < 4; rep++) {
            int idx = rep * 256 + t;
            int row = idx >> 4, g = idx & 15;
            *(short8*)&Qn[row * 136 + g * 8] = *(const short8*)&Qb[(n0c + row) * DD + g * 8];
        }
        // stage Vs: [128 d][64 n] from VT rows (contiguous)
#pragma unroll
        for (int rep = 0; rep < 4; rep++) {
            int idx = rep * 256 + t;
            int d = idx >> 3, g = idx & 7;
            *(short8*)&Vs[d * 72 + g * 8] = *(const short8*)&VTb[(size_t)d * NN + n0c + g * 8];
        }
        __syncthreads();

        // S stage: wave w owns n-band w*16; computes S[64 m][16 n]
        {
            short8 bq[4];
#pragma unroll
            for (int kd = 0; kd < 4; kd++)
                bq[kd] = *(short8*)&Qn[(w * 16 + l15) * 136 + kd * 32 + quad * 8];
#pragma unroll
            for (int ms = 0; ms < 4; ms++) {
                floatx4 s = (floatx4)(0.0f);
#pragma unroll
                for (int kd = 0; kd < 4; kd++)
                    s = __builtin_amdgcn_mfma_f32_16x16x32_bf16(qm[ms][kd], bq[kd], s, 0, 0, 0);
#pragma unroll
                for (int r = 0; r < 4; r++) {
                    float p = __expf(s[r] * RSCALE);
                    // row m = ms*16 + quad*4 + r, col n = w*16 + l15
                    Ps[(ms * 16 + quad * 4 + r) * 68 + w * 16 + l15] = f2bf(p);
                }
            }
        }
        __syncthreads();

        // PV stage: wave w owns d-band w*32; A = Vs rows d, B = Ps (k=n, col=m)
#pragma unroll
        for (int kn = 0; kn < 2; kn++) {
            short8 va0 = *(short8*)&Vs[(w * 32 + l15) * 72 + kn * 32 + quad * 8];
            short8 va1 = *(short8*)&Vs[(w * 32 + 16 + l15) * 72 + kn * 32 + quad * 8];
#pragma unroll
            for (int mf = 0; mf < 4; mf++) {
                short8 pb = *(short8*)&Ps[(mf * 16 + l15) * 68 + kn * 32 + quad * 8];
                acc[0][mf] = __builtin_amdgcn_mfma_f32_16x16x32_bf16(va0, pb, acc[0][mf], 0, 0, 0);
                acc[1][mf] = __builtin_amdgcn_mfma_f32_16x16x32_bf16(va1, pb, acc[1][mf], 0, 0, 0);
            }
        }
    }

    // store out[d][m0+m]; C-frag: col = m = mf*16+l15, row(d) = quad*4+r
    float* ob = out + (size_t)b * DD * NN;
#pragma unroll
    for (int dsub = 0; dsub < 2; dsub++)
#pragma unroll
        for (int mf = 0; mf < 4; mf++)
#pragma unroll
            for (int r = 0; r < 4; r++) {
                int d = w * 32 + dsub * 16 + quad * 4 + r;
                ob[(size_t)d * NN + m0 + mf * 16 + l15] = acc[dsub][mf][r];
            }
}

// ---------------------------------------------------------------------------
// Fallback path (small ws) — round-3 proven kernels
// ---------------------------------------------------------------------------
__global__ __launch_bounds__(256) void k1_fb(
    const float* __restrict__ x, const float* __restrict__ wqk,
    const float* __restrict__ wv, const float* __restrict__ bv,
    ushort* __restrict__ Q, ushort* __restrict__ V)
{
    const int nt = blockIdx.x;
    const int b  = blockIdx.y;
    const int n0 = nt * 32;
    const int t = threadIdx.x;
    const int lane = t & 63, w = t >> 6, l15 = lane & 15, quad = lane >> 4;

    __shared__ __attribute__((aligned(16))) ushort As[32 * 40];
    __shared__ __attribute__((aligned(16))) ushort Bs[256 * 40];

    floatx4 acc[2][4];
#pragma unroll
    for (int i = 0; i < 2; i++)
#pragma unroll
        for (int j = 0; j < 4; j++) acc[i][j] = (floatx4)(0.0f);

    const float* xb = x + b * (CH * NN) + n0;

    for (int c0 = 0; c0 < CH; c0 += 32) {
        {
            int n = t & 31, g = t >> 5;
            short4v v;
#pragma unroll
            for (int i = 0; i < 4; i++)
                v[i] = (short)f2bf(xb[(c0 + g * 4 + i) * NN + n]);
            *(short4v*)&As[n * 40 + g * 4] = v;
        }
#pragma unroll
        for (int rep = 0; rep < 16; rep++) {
            int idx = rep * 256 + t;
            int row = idx >> 4, cp = idx & 15;
            const float* wf = (row < 128) ? (wqk + row * CH) : (wv + (row - 128) * CH);
            uint pack = (uint)f2bf(wf[c0 + cp * 2]) | ((uint)f2bf(wf[c0 + cp * 2 + 1]) << 16);
            *(uint*)&Bs[row * 40 + cp * 2] = pack;
        }
        __syncthreads();
        short8 a0 = *(short8*)&As[(l15) * 40 + quad * 8];
        short8 a1 = *(short8*)&As[(16 + l15) * 40 + quad * 8];
#pragma unroll
        for (int dt2 = 0; dt2 < 4; dt2++) {
            short8 bf = *(short8*)&Bs[(w * 64 + dt2 * 16 + l15) * 40 + quad * 8];
            acc[0][dt2] = __builtin_amdgcn_mfma_f32_16x16x32_bf16(a0, bf, acc[0][dt2], 0, 0, 0);
            acc[1][dt2] = __builtin_amdgcn_mfma_f32_16x16x32_bf16(a1, bf, acc[1][dt2], 0, 0, 0);
        }
        __syncthreads();
    }
#pragma unroll
    for (int ns = 0; ns < 2; ns++)
#pragma unroll
        for (int dt2 = 0; dt2 < 4; dt2++) {
            int ds_ = w * 64 + dt2 * 16 + l15;
#pragma unroll
            for (int r = 0; r < 4; r++) {
                int n = n0 + ns * 16 + quad * 4 + r;
                float val = acc[ns][dt2][r];
                if (ds_ < 128) {
                    Q[b * (NN * DD) + n * DD + ds_] = f2bf(val);
                } else {
                    int dv = ds_ - 128;
                    V[b * (NN * DD) + n * DD + dv] = f2bf(val + bv[dv]);
                }
            }
        }
}

__global__ __launch_bounds__(256) void k2_norm(
    const ushort* __restrict__ Q, ushort* __restrict__ V)
{
    const int ntile = blockIdx.x;
    const int b = blockIdx.y;
    const int n0 = ntile * 64;
    const int t = threadIdx.x;
    const int lane = t & 63, w = t >> 6, l15 = lane & 15, quad = lane >> 4;

    __shared__ __attribute__((aligned(16))) ushort Qs[64 * 136];
    __shared__ __attribute__((aligned(16))) ushort Qm2[64 * 136];

    const ushort* Qb = Q + b * (NN * DD);

#pragma unroll
    for (int rep = 0; rep < 16; rep++) {
        int idx = rep * 256 + t;
        int row = idx >> 6, dp = idx & 63;
        *(uint*)&Qs[row * 136 + dp * 2] = *(const uint*)&Qb[(n0 + row) * DD + dp * 2];
    }
    __syncthreads();

    short8 afr[4];
#pragma unroll
    for (int kd = 0; kd < 4; kd++)
        afr[kd] = *(short8*)&Qs[(w * 16 + l15) * 136 + kd * 32 + quad * 8];

    float sums[4] = {0.f, 0.f, 0.f, 0.f};

    for (int m0 = 0; m0 < NN; m0 += 64) {
#pragma unroll
        for (int rep = 0; rep < 16; rep++) {
            int idx = rep * 256 + t;
            int row = idx >> 6, dp = idx & 63;
            *(uint*)&Qm2[row * 136 + dp * 2] = *(const uint*)&Qb[(m0 + row) * DD + dp * 2];
        }
        __syncthreads();
#pragma unroll
        for (int ct = 0; ct < 4; ct++) {
            floatx4 s = (floatx4)(0.0f);
#pragma unroll
            for (int kd = 0; kd < 4; kd++) {
                short8 bf = *(short8*)&Qm2[(ct * 16 + l15) * 136 + kd * 32 + quad * 8];
                s = __builtin_amdgcn_mfma_f32_16x16x32_bf16(afr[kd], bf, s, 0, 0, 0);
            }
#pragma unroll
            for (int r = 0; r < 4; r++)
                sums[r] += __expf(s[r] * RSCALE);
        }
        __syncthreads();
    }

#pragma unroll
    for (int r = 0; r < 4; r++) {
        float s = sums[r];
        s += __shfl_xor(s, 1);
        s += __shfl_xor(s, 2);
        s += __shfl_xor(s, 4);
        s += __shfl_xor(s, 8);
        sums[r] = s;
    }

    ushort* Vb = V + b * (NN * DD);
#pragma unroll
    for (int r = 0; r < 4; r++) {
        int n = n0 + w * 16 + quad * 4 + r;
        float inv = 1.0f / sums[r];
        short8 vv = *(short8*)&Vb[n * DD + l15 * 8];
        short8 o;
#pragma unroll
        for (int i = 0; i < 8; i++)
            o[i] = (short)f2bf(bf2f((ushort)vv[i]) * inv);
        *(short8*)&Vb[n * DD + l15 * 8] = o;
    }
}

__global__ __launch_bounds__(256) void k3_attn(
    const ushort* __restrict__ Q, const ushort* __restrict__ Vp,
    float* __restrict__ out)
{
    const int mtile = blockIdx.x;
    const int b = blockIdx.y;
    const int m0 = mtile * 64;
    const int t = threadIdx.x;
    const int lane = t & 63, w = t >> 6, l15 = lane & 15, quad = lane >> 4;

    __shared__ __attribute__((aligned(16))) ushort Qs[64 * 136];
    __shared__ __attribute__((aligned(16))) ushort Qn2[32 * 136];
    __shared__ __attribute__((aligned(16))) ushort Vs2[128 * 40];
    __shared__ __attribute__((aligned(16))) ushort Ps2[64 * 40];

    const ushort* Qb = Q + b * (NN * DD);
    const ushort* Vpb = Vp + b * (NN * DD);

#pragma unroll
    for (int rep = 0; rep < 16; rep++) {
        int idx = rep * 256 + t;
        int row = idx >> 6, dp = idx & 63;
        *(uint*)&Qs[row * 136 + dp * 2] = *(const uint*)&Qb[(m0 + row) * DD + dp * 2];
    }
    __syncthreads();

    short8 afr[4];
#pragma unroll
    for (int kd = 0; kd < 4; kd++)
        afr[kd] = *(short8*)&Qs[(w * 16 + l15) * 136 + kd * 32 + quad * 8];

    floatx4 acc[2][4];
#pragma unroll
    for (int s = 0; s < 2; s++)
#pragma unroll
        for (int mt = 0; mt < 4; mt++) acc[s][mt] = (floatx4)(0.0f);

    for (int n0c = 0; n0c < NN; n0c += 32) {
#pragma unroll
        for (int rep = 0; rep < 8; rep++) {
            int idx = rep * 256 + t;
            int row = idx >> 6, dp = idx & 63;
            *(uint*)&Qn2[row * 136 + dp * 2] = *(const uint*)&Qb[(n0c + row) * DD + dp * 2];
        }
#pragma unroll
        for (int rep = 0; rep < 8; rep++) {
            int idx = rep * 256 + t;
            int np = idx >> 7, d = idx & 127;
            uint v0 = Vpb[(n0c + np * 2) * DD + d];
            uint v1 = Vpb[(n0c + np * 2 + 1) * DD + d];
            *(uint*)&Vs2[d * 40 + np * 2] = v0 | (v1 << 16);
        }
        __syncthreads();

#pragma unroll
        for (int nt2 = 0; nt2 < 2; nt2++) {
            floatx4 s = (floatx4)(0.0f);
#pragma unroll
            for (int kd = 0; kd < 4; kd++) {
                short8 bf = *(short8*)&Qn2[(nt2 * 16 + l15) * 136 + kd * 32 + quad * 8];
                s = __builtin_amdgcn_mfma_f32_16x16x32_bf16(afr[kd], bf, s, 0, 0, 0);
            }
#pragma unroll
            for (int r = 0; r < 4; r++) {
                float p = __expf(s[r] * RSCALE);
                Ps2[(w * 16 + quad * 4 + r) * 40 + nt2 * 16 + l15] = f2bf(p);
            }
        }
        __syncthreads();

        short8 pb[4];
#pragma unroll
        for (int mt = 0; mt < 4; mt++)
            pb[mt] = *(short8*)&Ps2[(mt * 16 + l15) * 40 + quad * 8];
#pragma unroll
        for (int sub = 0; sub < 2; sub++) {
            short8 va = *(short8*)&Vs2[(w * 32 + sub * 16 + l15) * 40 + quad * 8];
#pragma unroll
            for (int mt = 0; mt < 4; mt++)
                acc[sub][mt] = __builtin_amdgcn_mfma_f32_16x16x32_bf16(va, pb[mt], acc[sub][mt], 0, 0, 0);
        }
        __syncthreads();
    }

    float* ob = out + (size_t)b * DD * NN;
#pragma unroll
    for (int sub = 0; sub < 2; sub++)
#pragma unroll
        for (int mt = 0; mt < 4; mt++)
#pragma unroll
            for (int r = 0; r < 4; r++) {
                int d = w * 32 + sub * 16 + quad * 4 + r;
                int m = m0 + mt * 16 + l15;
                ob[(size_t)d * NN + m] = acc[sub][mt][r];
            }
}

extern "C" void kernel_launch(void* const* d_in, const int* in_sizes, int n_in,
                              void* d_out, int out_size, void* d_ws, size_t ws_size,
                              hipStream_t stream) {
    const float* x   = (const float*)d_in[0];
    const float* wqk = (const float*)d_in[1];
    const float* wv  = (const float*)d_in[2];
    const float* bv  = (const float*)d_in[3];
    float* out = (float*)d_out;

    // ws: Q [0,4M) | V [4M,8M) | Wbf @8M (256K) | lsum @8M+256K (64K) | VT @12M (4M)
    ushort* Q = (ushort*)d_ws;
    ushort* V = (ushort*)((char*)d_ws + (4u << 20));

    if (ws_size >= (size_t)16 * 1024 * 1024) {
        ushort* Wbf  = (ushort*)((char*)d_ws + (8u << 20));
        float*  lsum = (float*)((char*)d_ws + (8u << 20) + (256u << 10));
        ushort* VT   = (ushort*)((char*)d_ws + (12u << 20));

        k0_prep<<<128, 256, 0, stream>>>(wqk, wv, Wbf, lsum);
        k1_proj<<<dim3(64, 8), 256, 0, stream>>>(x, Wbf, bv, Q, V);
        kl_sum<<<dim3(136, 8), 256, 0, stream>>>(Q, lsum);
        k2_scale_t<<<dim3(32, 8), 256, 0, stream>>>(V, lsum, VT);
        k_fused<<<dim3(32, 8), 256, 0, stream>>>(Q, VT, out);
    } else {
        k1_fb<<<dim3(64, 8), 256, 0, stream>>>(x, wqk, wv, bv, Q, V);
        k2_norm<<<dim3(32, 8), 256, 0, stream>>>(Q, V);
        k3_attn<<<dim3(32, 8), 256, 0, stream>>>(Q, V, out);
    }
}

// Round 9
// 156.483 us; speedup vs baseline: 1.2249x; 1.0745x over previous
//
#include <hip/hip_runtime.h>

typedef short short4v __attribute__((ext_vector_type(4)));
typedef short short8 __attribute__((ext_vector_type(8)));
typedef float floatx4 __attribute__((ext_vector_type(4)));
typedef unsigned int uint;
typedef unsigned short ushort;

#define CH 512
#define NN 2048
#define DD 128
#define RSCALE 0.08838834764831845f  // 1/sqrt(128)

__device__ __forceinline__ float bf2f(ushort u) {
    union { uint i; float f; } v; v.i = ((uint)u) << 16; return v.f;
}
__device__ __forceinline__ ushort f2bf(float f) {
    union { float f; uint u; } v; v.f = f;
    uint u = v.u;
    return (ushort)((u + 0x7fffu + ((u >> 16) & 1u)) >> 16);
}

// ---------------------------------------------------------------------------
// K0: weights -> bf16 AND zero lsum (merged; one launch)
// ---------------------------------------------------------------------------
__global__ __launch_bounds__(256) void k0_prep(
    const float* __restrict__ wqk, const float* __restrict__ wv,
    ushort* __restrict__ Wbf, float* __restrict__ lsum)
{
    int gid = blockIdx.x * 256 + threadIdx.x;  // 32768 threads
    int base = gid * 4;
    const float* src = (base < 65536) ? (wqk + base) : (wv + base - 65536);
    float4 v = *(const float4*)src;
    short4v o;
    o[0] = (short)f2bf(v.x); o[1] = (short)f2bf(v.y);
    o[2] = (short)f2bf(v.z); o[3] = (short)f2bf(v.w);
    *(short4v*)&Wbf[base] = o;
    if (gid < 16384) lsum[gid] = 0.0f;
}

// ---------------------------------------------------------------------------
// K1: projections, merged-d, bf16 weights. Block = [32 n][256 dstack].
// ---------------------------------------------------------------------------
__global__ __launch_bounds__(256) void k1_proj(
    const float* __restrict__ x,
    const ushort* __restrict__ Wbf,
    const float* __restrict__ bv,
    ushort* __restrict__ Q,
    ushort* __restrict__ V)
{
    const int nt = blockIdx.x;   // 0..63
    const int b  = blockIdx.y;   // 0..7
    const int n0 = nt * 32;
    const int t = threadIdx.x;
    const int lane = t & 63, w = t >> 6, l15 = lane & 15, quad = lane >> 4;

    __shared__ __attribute__((aligned(16))) ushort As[32 * 40];
    __shared__ __attribute__((aligned(16))) ushort Bs[256 * 40];

    floatx4 acc[2][4];
#pragma unroll
    for (int i = 0; i < 2; i++)
#pragma unroll
        for (int j = 0; j < 4; j++) acc[i][j] = (floatx4)(0.0f);

    const float* xb = x + b * (CH * NN) + n0;

    for (int c0 = 0; c0 < CH; c0 += 32) {
        {
            int n = t & 31, g = t >> 5;
            short4v v;
#pragma unroll
            for (int i = 0; i < 4; i++)
                v[i] = (short)f2bf(xb[(c0 + g * 4 + i) * NN + n]);
            *(short4v*)&As[n * 40 + g * 4] = v;
        }
#pragma unroll
        for (int rep = 0; rep < 16; rep++) {
            int idx = rep * 256 + t;
            int row = idx >> 4, cp = idx & 15;
            *(uint*)&Bs[row * 40 + cp * 2] = *(const uint*)&Wbf[row * CH + c0 + cp * 2];
        }
        __syncthreads();
        short8 a0 = *(short8*)&As[(l15) * 40 + quad * 8];
        short8 a1 = *(short8*)&As[(16 + l15) * 40 + quad * 8];
#pragma unroll
        for (int dt2 = 0; dt2 < 4; dt2++) {
            short8 bf = *(short8*)&Bs[(w * 64 + dt2 * 16 + l15) * 40 + quad * 8];
            acc[0][dt2] = __builtin_amdgcn_mfma_f32_16x16x32_bf16(a0, bf, acc[0][dt2], 0, 0, 0);
            acc[1][dt2] = __builtin_amdgcn_mfma_f32_16x16x32_bf16(a1, bf, acc[1][dt2], 0, 0, 0);
        }
        __syncthreads();
    }
#pragma unroll
    for (int ns = 0; ns < 2; ns++)
#pragma unroll
        for (int dt2 = 0; dt2 < 4; dt2++) {
            int ds_ = w * 64 + dt2 * 16 + l15;
#pragma unroll
            for (int r = 0; r < 4; r++) {
                int n = n0 + ns * 16 + quad * 4 + r;
                float val = acc[ns][dt2][r];
                if (ds_ < 128) {
                    Q[b * (NN * DD) + n * DD + ds_] = f2bf(val);
                } else {
                    int dv = ds_ - 128;
                    V[b * (NN * DD) + n * DD + dv] = f2bf(val + bv[dv]);
                }
            }
        }
}

// ---------------------------------------------------------------------------
// KL: l_n row sums via SYMMETRIC 128x128 S-tiles; only jt >= it computed.
// ---------------------------------------------------------------------------
__global__ __launch_bounds__(256) void kl_sum(
    const ushort* __restrict__ Q,   // [B][N][D] bf16
    float* __restrict__ lsum)       // [B][N]
{
    int pid = blockIdx.x;  // 0..135
    const int b = blockIdx.y;
    int it = 0;
    while (pid >= (16 - it)) { pid -= (16 - it); it++; }
    const int jt = it + pid;
    const int i0 = it * 128, j0 = jt * 128;
    const int t = threadIdx.x;
    const int lane = t & 63, w = t >> 6, l15 = lane & 15, quad = lane >> 4;
    const int wi = (w >> 1) * 64, wj = (w & 1) * 64;

    __shared__ __attribute__((aligned(16))) ushort Qi[128 * 136];
    __shared__ __attribute__((aligned(16))) ushort Qj[128 * 136];

    const ushort* Qb = Q + b * (NN * DD);

#pragma unroll
    for (int rep = 0; rep < 8; rep++) {
        int idx = rep * 256 + t;
        int row = idx >> 4, g = idx & 15;
        *(short8*)&Qi[row * 136 + g * 8] = *(const short8*)&Qb[(i0 + row) * DD + g * 8];
        *(short8*)&Qj[row * 136 + g * 8] = *(const short8*)&Qb[(j0 + row) * DD + g * 8];
    }
    __syncthreads();

    floatx4 acc[4][4];
#pragma unroll
    for (int i = 0; i < 4; i++)
#pragma unroll
        for (int j = 0; j < 4; j++) acc[i][j] = (floatx4)(0.0f);

#pragma unroll
    for (int kd = 0; kd < 4; kd++) {
        short8 afr[4], bfr[4];
#pragma unroll
        for (int nt = 0; nt < 4; nt++)
            afr[nt] = *(short8*)&Qi[(wi + nt * 16 + l15) * 136 + kd * 32 + quad * 8];
#pragma unroll
        for (int mt = 0; mt < 4; mt++)
            bfr[mt] = *(short8*)&Qj[(wj + mt * 16 + l15) * 136 + kd * 32 + quad * 8];
#pragma unroll
        for (int nt = 0; nt < 4; nt++)
#pragma unroll
            for (int mt = 0; mt < 4; mt++)
                acc[nt][mt] = __builtin_amdgcn_mfma_f32_16x16x32_bf16(afr[nt], bfr[mt], acc[nt][mt], 0, 0, 0);
    }

    float cs[4] = {0.f, 0.f, 0.f, 0.f};
#pragma unroll
    for (int nt = 0; nt < 4; nt++) {
        float rs[4] = {0.f, 0.f, 0.f, 0.f};
#pragma unroll
        for (int mt = 0; mt < 4; mt++)
#pragma unroll
            for (int r = 0; r < 4; r++) {
                float p = __expf(acc[nt][mt][r] * RSCALE);
                rs[r] += p;
                cs[mt] += p;
            }
#pragma unroll
        for (int r = 0; r < 4; r++) {
            float s = rs[r];
            s += __shfl_xor(s, 1);
            s += __shfl_xor(s, 2);
            s += __shfl_xor(s, 4);
            s += __shfl_xor(s, 8);
            if (l15 == 0)
                atomicAdd(&lsum[b * NN + i0 + wi + nt * 16 + quad * 4 + r], s);
        }
    }
    if (it != jt) {
#pragma unroll
        for (int mt = 0; mt < 4; mt++) {
            float s = cs[mt];
            s += __shfl_xor(s, 16);
            s += __shfl_xor(s, 32);
            if (lane < 16)
                atomicAdd(&lsum[b * NN + j0 + wj + mt * 16 + l15], s);
        }
    }
}

// ---------------------------------------------------------------------------
// K2c: VT[b][d][n] = V[b][n][d] / lsum[b][n]  (LDS transpose)
// ---------------------------------------------------------------------------
__global__ __launch_bounds__(256) void k2_scale_t(
    const ushort* __restrict__ V,
    const float* __restrict__ lsum,
    ushort* __restrict__ VT)
{
    const int nt = blockIdx.x;  // 0..31
    const int b = blockIdx.y;
    const int n0 = nt * 64;
    const int t = threadIdx.x;

    __shared__ __attribute__((aligned(16))) ushort Vt[64 * 132];

    const ushort* Vb = V + b * (NN * DD);
#pragma unroll
    for (int rep = 0; rep < 16; rep++) {
        int idx = rep * 256 + t;
        int row = idx >> 6, dp = idx & 63;
        *(uint*)&Vt[row * 132 + dp * 2] = *(const uint*)&Vb[(n0 + row) * DD + dp * 2];
    }
    __syncthreads();
#pragma unroll
    for (int rep = 0; rep < 16; rep++) {
        int idx = rep * 256 + t;
        int d = idx >> 5, col2 = idx & 31;
        int n = n0 + col2 * 2;
        float l0 = 1.0f / lsum[b * NN + n], l1 = 1.0f / lsum[b * NN + n + 1];
        float v0 = bf2f(Vt[(col2 * 2) * 132 + d]) * l0;
        float v1 = bf2f(Vt[(col2 * 2 + 1) * 132 + d]) * l1;
        uint pack = (uint)f2bf(v0) | ((uint)f2bf(v1) << 16);
        *(uint*)&VT[(size_t)b * DD * NN + (size_t)d * NN + n] = pack;
    }
}

// ---------------------------------------------------------------------------
// K3: FUSED attention, m-tile 64, n-SPLIT (2 halves -> partial buffers).
// Grid (32 mt, 2 half, 8 b) = 512 blocks -> 2 blocks/CU co-resident.
// ---------------------------------------------------------------------------
__global__ __launch_bounds__(256) void k_fused(
    const ushort* __restrict__ Q,   // [B][N][D] bf16
    const ushort* __restrict__ VT,  // [B][D][N] bf16 (V/l_n, transposed)
    float* __restrict__ part)       // [2][B][D][N] fp32 partials
{
    const int mt = blockIdx.x;  // 0..31
    const int h  = blockIdx.y;  // 0..1
    const int b  = blockIdx.z;
    const int m0 = mt * 64;
    const int t = threadIdx.x;
    const int lane = t & 63, w = t >> 6, l15 = lane & 15, quad = lane >> 4;

    __shared__ __attribute__((aligned(16))) ushort Qm[64 * 136];
    __shared__ __attribute__((aligned(16))) ushort Qn[64 * 136];
    __shared__ __attribute__((aligned(16))) ushort Vs[128 * 72];
    __shared__ __attribute__((aligned(16))) ushort Ps[64 * 68];

    const ushort* Qb = Q + b * (NN * DD);
    const ushort* VTb = VT + (size_t)b * DD * NN;

    // stage Qm (64 rows x 128 d)
#pragma unroll
    for (int rep = 0; rep < 4; rep++) {
        int idx = rep * 256 + t;
        int row = idx >> 4, g = idx & 15;
        *(short8*)&Qm[row * 136 + g * 8] = *(const short8*)&Qb[(m0 + row) * DD + g * 8];
    }
    __syncthreads();

    short8 qm[4][4];
#pragma unroll
    for (int ms = 0; ms < 4; ms++)
#pragma unroll
        for (int kd = 0; kd < 4; kd++)
            qm[ms][kd] = *(short8*)&Qm[(ms * 16 + l15) * 136 + kd * 32 + quad * 8];

    floatx4 acc[2][4];
#pragma unroll
    for (int i = 0; i < 2; i++)
#pragma unroll
        for (int j = 0; j < 4; j++) acc[i][j] = (floatx4)(0.0f);

    const int nbeg = h * (NN / 2), nend = nbeg + (NN / 2);
    for (int n0c = nbeg; n0c < nend; n0c += 64) {
        __syncthreads();
#pragma unroll
        for (int rep = 0; rep < 4; rep++) {
            int idx = rep * 256 + t;
            int row = idx >> 4, g = idx & 15;
            *(short8*)&Qn[row * 136 + g * 8] = *(const short8*)&Qb[(n0c + row) * DD + g * 8];
        }
#pragma unroll
        for (int rep = 0; rep < 4; rep++) {
            int idx = rep * 256 + t;
            int d = idx >> 3, g = idx & 7;
            *(short8*)&Vs[d * 72 + g * 8] = *(const short8*)&VTb[(size_t)d * NN + n0c + g * 8];
        }
        __syncthreads();

        // S stage: wave w owns n-band w*16; computes S[64 m][16 n]
        {
            short8 bq[4];
#pragma unroll
            for (int kd = 0; kd < 4; kd++)
                bq[kd] = *(short8*)&Qn[(w * 16 + l15) * 136 + kd * 32 + quad * 8];
#pragma unroll
            for (int ms = 0; ms < 4; ms++) {
                floatx4 s = (floatx4)(0.0f);
#pragma unroll
                for (int kd = 0; kd < 4; kd++)
                    s = __builtin_amdgcn_mfma_f32_16x16x32_bf16(qm[ms][kd], bq[kd], s, 0, 0, 0);
#pragma unroll
                for (int r = 0; r < 4; r++) {
                    float p = __expf(s[r] * RSCALE);
                    Ps[(ms * 16 + quad * 4 + r) * 68 + w * 16 + l15] = f2bf(p);
                }
            }
        }
        __syncthreads();

        // PV stage: wave w owns d-band w*32
#pragma unroll
        for (int kn = 0; kn < 2; kn++) {
            short8 va0 = *(short8*)&Vs[(w * 32 + l15) * 72 + kn * 32 + quad * 8];
            short8 va1 = *(short8*)&Vs[(w * 32 + 16 + l15) * 72 + kn * 32 + quad * 8];
#pragma unroll
            for (int mf = 0; mf < 4; mf++) {
                short8 pb = *(short8*)&Ps[(mf * 16 + l15) * 68 + kn * 32 + quad * 8];
                acc[0][mf] = __builtin_amdgcn_mfma_f32_16x16x32_bf16(va0, pb, acc[0][mf], 0, 0, 0);
                acc[1][mf] = __builtin_amdgcn_mfma_f32_16x16x32_bf16(va1, pb, acc[1][mf], 0, 0, 0);
            }
        }
    }

    float* ob = part + (size_t)h * (8 * DD * NN) + (size_t)b * DD * NN;
#pragma unroll
    for (int dsub = 0; dsub < 2; dsub++)
#pragma unroll
        for (int mf = 0; mf < 4; mf++)
#pragma unroll
            for (int r = 0; r < 4; r++) {
                int d = w * 32 + dsub * 16 + quad * 4 + r;
                ob[(size_t)d * NN + m0 + mf * 16 + l15] = acc[dsub][mf][r];
            }
}

// ---------------------------------------------------------------------------
// K4: out = part0 + part1  (2M floats)
// ---------------------------------------------------------------------------
__global__ __launch_bounds__(256) void k_reduce(
    const float* __restrict__ part, float* __restrict__ out)
{
    int gid = blockIdx.x * 256 + threadIdx.x;
    const size_t half = (size_t)8 * DD * NN;
    float4 a = *(const float4*)&part[gid * 4];
    float4 b = *(const float4*)&part[half + gid * 4];
    float4 o;
    o.x = a.x + b.x; o.y = a.y + b.y; o.z = a.z + b.z; o.w = a.w + b.w;
    *(float4*)&out[gid * 4] = o;
}

// ---------------------------------------------------------------------------
// Fallback path (small ws) — round-3 proven kernels
// ---------------------------------------------------------------------------
__global__ __launch_bounds__(256) void k1_fb(
    const float* __restrict__ x, const float* __restrict__ wqk,
    const float* __restrict__ wv, const float* __restrict__ bv,
    ushort* __restrict__ Q, ushort* __restrict__ V)
{
    const int nt = blockIdx.x;
    const int b  = blockIdx.y;
    const int n0 = nt * 32;
    const int t = threadIdx.x;
    const int lane = t & 63, w = t >> 6, l15 = lane & 15, quad = lane >> 4;

    __shared__ __attribute__((aligned(16))) ushort As[32 * 40];
    __shared__ __attribute__((aligned(16))) ushort Bs[256 * 40];

    floatx4 acc[2][4];
#pragma unroll
    for (int i = 0; i < 2; i++)
#pragma unroll
        for (int j = 0; j < 4; j++) acc[i][j] = (floatx4)(0.0f);

    const float* xb = x + b * (CH * NN) + n0;

    for (int c0 = 0; c0 < CH; c0 += 32) {
        {
            int n = t & 31, g = t >> 5;
            short4v v;
#pragma unroll
            for (int i = 0; i < 4; i++)
                v[i] = (short)f2bf(xb[(c0 + g * 4 + i) * NN + n]);
            *(short4v*)&As[n * 40 + g * 4] = v;
        }
#pragma unroll
        for (int rep = 0; rep < 16; rep++) {
            int idx = rep * 256 + t;
            int row = idx >> 4, cp = idx & 15;
            const float* wf = (row < 128) ? (wqk + row * CH) : (wv + (row - 128) * CH);
            uint pack = (uint)f2bf(wf[c0 + cp * 2]) | ((uint)f2bf(wf[c0 + cp * 2 + 1]) << 16);
            *(uint*)&Bs[row * 40 + cp * 2] = pack;
        }
        __syncthreads();
        short8 a0 = *(short8*)&As[(l15) * 40 + quad * 8];
        short8 a1 = *(short8*)&As[(16 + l15) * 40 + quad * 8];
#pragma unroll
        for (int dt2 = 0; dt2 < 4; dt2++) {
            short8 bf = *(short8*)&Bs[(w * 64 + dt2 * 16 + l15) * 40 + quad * 8];
            acc[0][dt2] = __builtin_amdgcn_mfma_f32_16x16x32_bf16(a0, bf, acc[0][dt2], 0, 0, 0);
            acc[1][dt2] = __builtin_amdgcn_mfma_f32_16x16x32_bf16(a1, bf, acc[1][dt2], 0, 0, 0);
        }
        __syncthreads();
    }
#pragma unroll
    for (int ns = 0; ns < 2; ns++)
#pragma unroll
        for (int dt2 = 0; dt2 < 4; dt2++) {
            int ds_ = w * 64 + dt2 * 16 + l15;
#pragma unroll
            for (int r = 0; r < 4; r++) {
                int n = n0 + ns * 16 + quad * 4 + r;
                float val = acc[ns][dt2][r];
                if (ds_ < 128) {
                    Q[b * (NN * DD) + n * DD + ds_] = f2bf(val);
                } else {
                    int dv = ds_ - 128;
                    V[b * (NN * DD) + n * DD + dv] = f2bf(val + bv[dv]);
                }
            }
        }
}

__global__ __launch_bounds__(256) void k2_norm(
    const ushort* __restrict__ Q, ushort* __restrict__ V)
{
    const int ntile = blockIdx.x;
    const int b = blockIdx.y;
    const int n0 = ntile * 64;
    const int t = threadIdx.x;
    const int lane = t & 63, w = t >> 6, l15 = lane & 15, quad = lane >> 4;

    __shared__ __attribute__((aligned(16))) ushort Qs[64 * 136];
    __shared__ __attribute__((aligned(16))) ushort Qm2[64 * 136];

    const ushort* Qb = Q + b * (NN * DD);

#pragma unroll
    for (int rep = 0; rep < 16; rep++) {
        int idx = rep * 256 + t;
        int row = idx >> 6, dp = idx & 63;
        *(uint*)&Qs[row * 136 + dp * 2] = *(const uint*)&Qb[(n0 + row) * DD + dp * 2];
    }
    __syncthreads();

    short8 afr[4];
#pragma unroll
    for (int kd = 0; kd < 4; kd++)
        afr[kd] = *(short8*)&Qs[(w * 16 + l15) * 136 + kd * 32 + quad * 8];

    float sums[4] = {0.f, 0.f, 0.f, 0.f};

    for (int m0 = 0; m0 < NN; m0 += 64) {
#pragma unroll
        for (int rep = 0; rep < 16; rep++) {
            int idx = rep * 256 + t;
            int row = idx >> 6, dp = idx & 63;
            *(uint*)&Qm2[row * 136 + dp * 2] = *(const uint*)&Qb[(m0 + row) * DD + dp * 2];
        }
        __syncthreads();
#pragma unroll
        for (int ct = 0; ct < 4; ct++) {
            floatx4 s = (floatx4)(0.0f);
#pragma unroll
            for (int kd = 0; kd < 4; kd++) {
                short8 bf = *(short8*)&Qm2[(ct * 16 + l15) * 136 + kd * 32 + quad * 8];
                s = __builtin_amdgcn_mfma_f32_16x16x32_bf16(afr[kd], bf, s, 0, 0, 0);
            }
#pragma unroll
            for (int r = 0; r < 4; r++)
                sums[r] += __expf(s[r] * RSCALE);
        }
        __syncthreads();
    }

#pragma unroll
    for (int r = 0; r < 4; r++) {
        float s = sums[r];
        s += __shfl_xor(s, 1);
        s += __shfl_xor(s, 2);
        s += __shfl_xor(s, 4);
        s += __shfl_xor(s, 8);
        sums[r] = s;
    }

    ushort* Vb = V + b * (NN * DD);
#pragma unroll
    for (int r = 0; r < 4; r++) {
        int n = n0 + w * 16 + quad * 4 + r;
        float inv = 1.0f / sums[r];
        short8 vv = *(short8*)&Vb[n * DD + l15 * 8];
        short8 o;
#pragma unroll
        for (int i = 0; i < 8; i++)
            o[i] = (short)f2bf(bf2f((ushort)vv[i]) * inv);
        *(short8*)&Vb[n * DD + l15 * 8] = o;
    }
}

__global__ __launch_bounds__(256) void k3_attn(
    const ushort* __restrict__ Q, const ushort* __restrict__ Vp,
    float* __restrict__ out)
{
    const int mtile = blockIdx.x;
    const int b = blockIdx.y;
    const int m0 = mtile * 64;
    const int t = threadIdx.x;
    const int lane = t & 63, w = t >> 6, l15 = lane & 15, quad = lane >> 4;

    __shared__ __attribute__((aligned(16))) ushort Qs[64 * 136];
    __shared__ __attribute__((aligned(16))) ushort Qn2[32 * 136];
    __shared__ __attribute__((aligned(16))) ushort Vs2[128 * 40];
    __shared__ __attribute__((aligned(16))) ushort Ps2[64 * 40];

    const ushort* Qb = Q + b * (NN * DD);
    const ushort* Vpb = Vp + b * (NN * DD);

#pragma unroll
    for (int rep = 0; rep < 16; rep++) {
        int idx = rep * 256 + t;
        int row = idx >> 6, dp = idx & 63;
        *(uint*)&Qs[row * 136 + dp * 2] = *(const uint*)&Qb[(m0 + row) * DD + dp * 2];
    }
    __syncthreads();

    short8 afr[4];
#pragma unroll
    for (int kd = 0; kd < 4; kd++)
        afr[kd] = *(short8*)&Qs[(w * 16 + l15) * 136 + kd * 32 + quad * 8];

    floatx4 acc[2][4];
#pragma unroll
    for (int s = 0; s < 2; s++)
#pragma unroll
        for (int mt = 0; mt < 4; mt++) acc[s][mt] = (floatx4)(0.0f);

    for (int n0c = 0; n0c < NN; n0c += 32) {
#pragma unroll
        for (int rep = 0; rep < 8; rep++) {
            int idx = rep * 256 + t;
            int row = idx >> 6, dp = idx & 63;
            *(uint*)&Qn2[row * 136 + dp * 2] = *(const uint*)&Qb[(n0c + row) * DD + dp * 2];
        }
#pragma unroll
        for (int rep = 0; rep < 8; rep++) {
            int idx = rep * 256 + t;
            int np = idx >> 7, d = idx & 127;
            uint v0 = Vpb[(n0c + np * 2) * DD + d];
            uint v1 = Vpb[(n0c + np * 2 + 1) * DD + d];
            *(uint*)&Vs2[d * 40 + np * 2] = v0 | (v1 << 16);
        }
        __syncthreads();

#pragma unroll
        for (int nt2 = 0; nt2 < 2; nt2++) {
            floatx4 s = (floatx4)(0.0f);
#pragma unroll
            for (int kd = 0; kd < 4; kd++) {
                short8 bf = *(short8*)&Qn2[(nt2 * 16 + l15) * 136 + kd * 32 + quad * 8];
                s = __builtin_amdgcn_mfma_f32_16x16x32_bf16(afr[kd], bf, s, 0, 0, 0);
            }
#pragma unroll
            for (int r = 0; r < 4; r++) {
                float p = __expf(s[r] * RSCALE);
                Ps2[(w * 16 + quad * 4 + r) * 40 + nt2 * 16 + l15] = f2bf(p);
            }
        }
        __syncthreads();

        short8 pb[4];
#pragma unroll
        for (int mt = 0; mt < 4; mt++)
            pb[mt] = *(short8*)&Ps2[(mt * 16 + l15) * 40 + quad * 8];
#pragma unroll
        for (int sub = 0; sub < 2; sub++) {
            short8 va = *(short8*)&Vs2[(w * 32 + sub * 16 + l15) * 40 + quad * 8];
#pragma unroll
            for (int mt = 0; mt < 4; mt++)
                acc[sub][mt] = __builtin_amdgcn_mfma_f32_16x16x32_bf16(va, pb[mt], acc[sub][mt], 0, 0, 0);
        }
        __syncthreads();
    }

    float* ob = out + (size_t)b * DD * NN;
#pragma unroll
    for (int sub = 0; sub < 2; sub++)
#pragma unroll
        for (int mt = 0; mt < 4; mt++)
#pragma unroll
            for (int r = 0; r < 4; r++) {
                int d = w * 32 + sub * 16 + quad * 4 + r;
                int m = m0 + mt * 16 + l15;
                ob[(size_t)d * NN + m] = acc[sub][mt][r];
            }
}

extern "C" void kernel_launch(void* const* d_in, const int* in_sizes, int n_in,
                              void* d_out, int out_size, void* d_ws, size_t ws_size,
                              hipStream_t stream) {
    const float* x   = (const float*)d_in[0];
    const float* wqk = (const float*)d_in[1];
    const float* wv  = (const float*)d_in[2];
    const float* bv  = (const float*)d_in[3];
    float* out = (float*)d_out;

    // ws: Q [0,4M) | V [4M,8M) | Wbf @8M (256K) | lsum @8M+256K (64K)
    //   | VT @12M (4M) | part @16M (16M)  -> 32 MiB total
    //   (ws >= 80 MiB verified: rounds 4-5 executed the 80 MiB-gated path)
    ushort* Q = (ushort*)d_ws;
    ushort* V = (ushort*)((char*)d_ws + (4u << 20));

    if (ws_size >= (size_t)33 * 1024 * 1024) {
        ushort* Wbf  = (ushort*)((char*)d_ws + (8u << 20));
        float*  lsum = (float*)((char*)d_ws + (8u << 20) + (256u << 10));
        ushort* VT   = (ushort*)((char*)d_ws + (12u << 20));
        float*  part = (float*)((char*)d_ws + (16u << 20));

        k0_prep<<<128, 256, 0, stream>>>(wqk, wv, Wbf, lsum);
        k1_proj<<<dim3(64, 8), 256, 0, stream>>>(x, Wbf, bv, Q, V);
        kl_sum<<<dim3(136, 8), 256, 0, stream>>>(Q, lsum);
        k2_scale_t<<<dim3(32, 8), 256, 0, stream>>>(V, lsum, VT);
        k_fused<<<dim3(32, 2, 8), 256, 0, stream>>>(Q, VT, part);
        k_reduce<<<2048, 256, 0, stream>>>(part, out);
    } else {
        k1_fb<<<dim3(64, 8), 256, 0, stream>>>(x, wqk, wv, bv, Q, V);
        k2_norm<<<dim3(32, 8), 256, 0, stream>>>(Q, V);
        k3_attn<<<dim3(32, 8), 256, 0, stream>>>(Q, V, out);
    }
}

// Round 10
// 152.230 us; speedup vs baseline: 1.2591x; 1.0279x over previous
//
#include <hip/hip_runtime.h>

typedef short short4v __attribute__((ext_vector_type(4)));
typedef short short8 __attribute__((ext_vector_type(8)));
typedef float floatx4 __attribute__((ext_vector_type(4)));
typedef unsigned int uint;
typedef unsigned short ushort;

#define CH 512
#define NN 2048
#define DD 128
#define RSCALE 0.08838834764831845f  // 1/sqrt(128)

__device__ __forceinline__ float bf2f(ushort u) {
    union { uint i; float f; } v; v.i = ((uint)u) << 16; return v.f;
}
__device__ __forceinline__ ushort f2bf(float f) {
    union { float f; uint u; } v; v.f = f;
    uint u = v.u;
    return (ushort)((u + 0x7fffu + ((u >> 16) & 1u)) >> 16);
}

// ---------------------------------------------------------------------------
// K0: weights -> bf16 AND zero lsum (merged; one launch)
// ---------------------------------------------------------------------------
__global__ __launch_bounds__(256) void k0_prep(
    const float* __restrict__ wqk, const float* __restrict__ wv,
    ushort* __restrict__ Wbf, float* __restrict__ lsum)
{
    int gid = blockIdx.x * 256 + threadIdx.x;  // 32768 threads
    int base = gid * 4;
    const float* src = (base < 65536) ? (wqk + base) : (wv + base - 65536);
    float4 v = *(const float4*)src;
    short4v o;
    o[0] = (short)f2bf(v.x); o[1] = (short)f2bf(v.y);
    o[2] = (short)f2bf(v.z); o[3] = (short)f2bf(v.w);
    *(short4v*)&Wbf[base] = o;
    if (gid < 16384) lsum[gid] = 0.0f;
}

// ---------------------------------------------------------------------------
// K1: projections, merged-d, bf16 weights. Block = [32 n][256 dstack].
// Writes Q[b][n][d] AND V transposed+biased directly: VT[b][d][n] (unscaled).
// ---------------------------------------------------------------------------
__global__ __launch_bounds__(256) void k1_proj(
    const float* __restrict__ x,
    const ushort* __restrict__ Wbf,
    const float* __restrict__ bv,
    ushort* __restrict__ Q,
    ushort* __restrict__ VT)
{
    const int nt = blockIdx.x;   // 0..63
    const int b  = blockIdx.y;   // 0..7
    const int n0 = nt * 32;
    const int t = threadIdx.x;
    const int lane = t & 63, w = t >> 6, l15 = lane & 15, quad = lane >> 4;

    __shared__ __attribute__((aligned(16))) ushort As[32 * 40];
    __shared__ __attribute__((aligned(16))) ushort Bs[256 * 40];
    __shared__ __attribute__((aligned(16))) ushort Vt[128 * 40];

    floatx4 acc[2][4];
#pragma unroll
    for (int i = 0; i < 2; i++)
#pragma unroll
        for (int j = 0; j < 4; j++) acc[i][j] = (floatx4)(0.0f);

    const float* xb = x + b * (CH * NN) + n0;

    for (int c0 = 0; c0 < CH; c0 += 32) {
        // stage A: [32 n][32 c], fp32 -> bf16
        {
            int n = t & 31, g = t >> 5;
            short4v v;
#pragma unroll
            for (int i = 0; i < 4; i++)
                v[i] = (short)f2bf(xb[(c0 + g * 4 + i) * NN + n]);
            *(short4v*)&As[n * 40 + g * 4] = v;
        }
        // stage B: [256 dstack][32 c], short8 copies (4 reps)
#pragma unroll
        for (int rep = 0; rep < 4; rep++) {
            int idx = rep * 256 + t;
            int row = idx >> 2, g = idx & 3;
            *(short8*)&Bs[row * 40 + g * 8] = *(const short8*)&Wbf[row * CH + c0 + g * 8];
        }
        __syncthreads();
        short8 a0 = *(short8*)&As[(l15) * 40 + quad * 8];
        short8 a1 = *(short8*)&As[(16 + l15) * 40 + quad * 8];
#pragma unroll
        for (int dt2 = 0; dt2 < 4; dt2++) {
            short8 bf = *(short8*)&Bs[(w * 64 + dt2 * 16 + l15) * 40 + quad * 8];
            acc[0][dt2] = __builtin_amdgcn_mfma_f32_16x16x32_bf16(a0, bf, acc[0][dt2], 0, 0, 0);
            acc[1][dt2] = __builtin_amdgcn_mfma_f32_16x16x32_bf16(a1, bf, acc[1][dt2], 0, 0, 0);
        }
        __syncthreads();
    }

    // epilogue: waves 0,1 -> Q stores; waves 2,3 -> V (+bias) into LDS transpose
#pragma unroll
    for (int ns = 0; ns < 2; ns++)
#pragma unroll
        for (int dt2 = 0; dt2 < 4; dt2++) {
            int ds_ = w * 64 + dt2 * 16 + l15;
#pragma unroll
            for (int r = 0; r < 4; r++) {
                int nl = ns * 16 + quad * 4 + r;
                float val = acc[ns][dt2][r];
                if (ds_ < 128) {
                    Q[b * (NN * DD) + (n0 + nl) * DD + ds_] = f2bf(val);
                } else {
                    int dv = ds_ - 128;
                    Vt[dv * 40 + nl] = f2bf(val + bv[dv]);
                }
            }
        }
    __syncthreads();
    // cooperative store: VT[b][dv][n0..n0+32], 16 B per thread x 2 reps
#pragma unroll
    for (int rep = 0; rep < 2; rep++) {
        int idx = rep * 256 + t;
        int dv = idx >> 2, seg = idx & 3;
        *(short8*)&VT[((size_t)b * DD + dv) * NN + n0 + seg * 8] =
            *(short8*)&Vt[dv * 40 + seg * 8];
    }
}

// ---------------------------------------------------------------------------
// KL: l_n row sums via SYMMETRIC 128x128 S-tiles; only jt >= it computed.
// ---------------------------------------------------------------------------
__global__ __launch_bounds__(256) void kl_sum(
    const ushort* __restrict__ Q,   // [B][N][D] bf16
    float* __restrict__ lsum)       // [B][N]
{
    int pid = blockIdx.x;  // 0..135
    const int b = blockIdx.y;
    int it = 0;
    while (pid >= (16 - it)) { pid -= (16 - it); it++; }
    const int jt = it + pid;
    const int i0 = it * 128, j0 = jt * 128;
    const int t = threadIdx.x;
    const int lane = t & 63, w = t >> 6, l15 = lane & 15, quad = lane >> 4;
    const int wi = (w >> 1) * 64, wj = (w & 1) * 64;

    __shared__ __attribute__((aligned(16))) ushort Qi[128 * 136];
    __shared__ __attribute__((aligned(16))) ushort Qj[128 * 136];

    const ushort* Qb = Q + b * (NN * DD);

#pragma unroll
    for (int rep = 0; rep < 8; rep++) {
        int idx = rep * 256 + t;
        int row = idx >> 4, g = idx & 15;
        *(short8*)&Qi[row * 136 + g * 8] = *(const short8*)&Qb[(i0 + row) * DD + g * 8];
        *(short8*)&Qj[row * 136 + g * 8] = *(const short8*)&Qb[(j0 + row) * DD + g * 8];
    }
    __syncthreads();

    floatx4 acc[4][4];
#pragma unroll
    for (int i = 0; i < 4; i++)
#pragma unroll
        for (int j = 0; j < 4; j++) acc[i][j] = (floatx4)(0.0f);

#pragma unroll
    for (int kd = 0; kd < 4; kd++) {
        short8 afr[4], bfr[4];
#pragma unroll
        for (int nt = 0; nt < 4; nt++)
            afr[nt] = *(short8*)&Qi[(wi + nt * 16 + l15) * 136 + kd * 32 + quad * 8];
#pragma unroll
        for (int mt = 0; mt < 4; mt++)
            bfr[mt] = *(short8*)&Qj[(wj + mt * 16 + l15) * 136 + kd * 32 + quad * 8];
#pragma unroll
        for (int nt = 0; nt < 4; nt++)
#pragma unroll
            for (int mt = 0; mt < 4; mt++)
                acc[nt][mt] = __builtin_amdgcn_mfma_f32_16x16x32_bf16(afr[nt], bfr[mt], acc[nt][mt], 0, 0, 0);
    }

    float cs[4] = {0.f, 0.f, 0.f, 0.f};
#pragma unroll
    for (int nt = 0; nt < 4; nt++) {
        float rs[4] = {0.f, 0.f, 0.f, 0.f};
#pragma unroll
        for (int mt = 0; mt < 4; mt++)
#pragma unroll
            for (int r = 0; r < 4; r++) {
                float p = __expf(acc[nt][mt][r] * RSCALE);
                rs[r] += p;
                cs[mt] += p;
            }
#pragma unroll
        for (int r = 0; r < 4; r++) {
            float s = rs[r];
            s += __shfl_xor(s, 1);
            s += __shfl_xor(s, 2);
            s += __shfl_xor(s, 4);
            s += __shfl_xor(s, 8);
            if (l15 == 0)
                atomicAdd(&lsum[b * NN + i0 + wi + nt * 16 + quad * 4 + r], s);
        }
    }
    if (it != jt) {
#pragma unroll
        for (int mt = 0; mt < 4; mt++) {
            float s = cs[mt];
            s += __shfl_xor(s, 16);
            s += __shfl_xor(s, 32);
            if (lane < 16)
                atomicAdd(&lsum[b * NN + j0 + wj + mt * 16 + l15], s);
        }
    }
}

// ---------------------------------------------------------------------------
// K3: FUSED attention, m-tile 64, n-SPLIT (2 halves -> partial buffers).
// 1/l_n folded into the Ps write (V stays unscaled).
// ---------------------------------------------------------------------------
__global__ __launch_bounds__(256) void k_fused(
    const ushort* __restrict__ Q,   // [B][N][D] bf16
    const ushort* __restrict__ VT,  // [B][D][N] bf16 (unscaled, +bias)
    const float* __restrict__ lsum, // [B][N]
    float* __restrict__ part)       // [2][B][D][N] fp32 partials
{
    const int mt = blockIdx.x;  // 0..31
    const int h  = blockIdx.y;  // 0..1
    const int b  = blockIdx.z;
    const int m0 = mt * 64;
    const int t = threadIdx.x;
    const int lane = t & 63, w = t >> 6, l15 = lane & 15, quad = lane >> 4;

    __shared__ __attribute__((aligned(16))) ushort Qm[64 * 136];
    __shared__ __attribute__((aligned(16))) ushort Qn[64 * 136];
    __shared__ __attribute__((aligned(16))) ushort Vs[128 * 72];
    __shared__ __attribute__((aligned(16))) ushort Ps[64 * 68];

    const ushort* Qb = Q + b * (NN * DD);
    const ushort* VTb = VT + (size_t)b * DD * NN;
    const float* lb = lsum + b * NN;

    // stage Qm (64 rows x 128 d)
#pragma unroll
    for (int rep = 0; rep < 4; rep++) {
        int idx = rep * 256 + t;
        int row = idx >> 4, g = idx & 15;
        *(short8*)&Qm[row * 136 + g * 8] = *(const short8*)&Qb[(m0 + row) * DD + g * 8];
    }
    __syncthreads();

    short8 qm[4][4];
#pragma unroll
    for (int ms = 0; ms < 4; ms++)
#pragma unroll
        for (int kd = 0; kd < 4; kd++)
            qm[ms][kd] = *(short8*)&Qm[(ms * 16 + l15) * 136 + kd * 32 + quad * 8];

    floatx4 acc[2][4];
#pragma unroll
    for (int i = 0; i < 2; i++)
#pragma unroll
        for (int j = 0; j < 4; j++) acc[i][j] = (floatx4)(0.0f);

    const int nbeg = h * (NN / 2), nend = nbeg + (NN / 2);
    for (int n0c = nbeg; n0c < nend; n0c += 64) {
        float lw = lb[n0c + w * 16 + l15];  // normalizer for this lane's n-col
        __syncthreads();
#pragma unroll
        for (int rep = 0; rep < 4; rep++) {
            int idx = rep * 256 + t;
            int row = idx >> 4, g = idx & 15;
            *(short8*)&Qn[row * 136 + g * 8] = *(const short8*)&Qb[(n0c + row) * DD + g * 8];
        }
#pragma unroll
        for (int rep = 0; rep < 4; rep++) {
            int idx = rep * 256 + t;
            int d = idx >> 3, g = idx & 7;
            *(short8*)&Vs[d * 72 + g * 8] = *(const short8*)&VTb[(size_t)d * NN + n0c + g * 8];
        }
        __syncthreads();

        // S stage: wave w owns n-band w*16; computes S[64 m][16 n]
        {
            float linv = 1.0f / lw;
            short8 bq[4];
#pragma unroll
            for (int kd = 0; kd < 4; kd++)
                bq[kd] = *(short8*)&Qn[(w * 16 + l15) * 136 + kd * 32 + quad * 8];
#pragma unroll
            for (int ms = 0; ms < 4; ms++) {
                floatx4 s = (floatx4)(0.0f);
#pragma unroll
                for (int kd = 0; kd < 4; kd++)
                    s = __builtin_amdgcn_mfma_f32_16x16x32_bf16(qm[ms][kd], bq[kd], s, 0, 0, 0);
#pragma unroll
                for (int r = 0; r < 4; r++) {
                    float p = __expf(s[r] * RSCALE) * linv;
                    Ps[(ms * 16 + quad * 4 + r) * 68 + w * 16 + l15] = f2bf(p);
                }
            }
        }
        __syncthreads();

        // PV stage: wave w owns d-band w*32
#pragma unroll
        for (int kn = 0; kn < 2; kn++) {
            short8 va0 = *(short8*)&Vs[(w * 32 + l15) * 72 + kn * 32 + quad * 8];
            short8 va1 = *(short8*)&Vs[(w * 32 + 16 + l15) * 72 + kn * 32 + quad * 8];
#pragma unroll
            for (int mf = 0; mf < 4; mf++) {
                short8 pb = *(short8*)&Ps[(mf * 16 + l15) * 68 + kn * 32 + quad * 8];
                acc[0][mf] = __builtin_amdgcn_mfma_f32_16x16x32_bf16(va0, pb, acc[0][mf], 0, 0, 0);
                acc[1][mf] = __builtin_amdgcn_mfma_f32_16x16x32_bf16(va1, pb, acc[1][mf], 0, 0, 0);
            }
        }
    }

    float* ob = part + (size_t)h * (8 * DD * NN) + (size_t)b * DD * NN;
#pragma unroll
    for (int dsub = 0; dsub < 2; dsub++)
#pragma unroll
        for (int mf = 0; mf < 4; mf++)
#pragma unroll
            for (int r = 0; r < 4; r++) {
                int d = w * 32 + dsub * 16 + quad * 4 + r;
                ob[(size_t)d * NN + m0 + mf * 16 + l15] = acc[dsub][mf][r];
            }
}

// ---------------------------------------------------------------------------
// K4: out = part0 + part1  (2M floats)
// ---------------------------------------------------------------------------
__global__ __launch_bounds__(256) void k_reduce(
    const float* __restrict__ part, float* __restrict__ out)
{
    int gid = blockIdx.x * 256 + threadIdx.x;
    const size_t half = (size_t)8 * DD * NN;
    float4 a = *(const float4*)&part[gid * 4];
    float4 b = *(const float4*)&part[half + gid * 4];
    float4 o;
    o.x = a.x + b.x; o.y = a.y + b.y; o.z = a.z + b.z; o.w = a.w + b.w;
    *(float4*)&out[gid * 4] = o;
}

// ---------------------------------------------------------------------------
// Fallback path (small ws) — round-3 proven kernels
// ---------------------------------------------------------------------------
__global__ __launch_bounds__(256) void k1_fb(
    const float* __restrict__ x, const float* __restrict__ wqk,
    const float* __restrict__ wv, const float* __restrict__ bv,
    ushort* __restrict__ Q, ushort* __restrict__ V)
{
    const int nt = blockIdx.x;
    const int b  = blockIdx.y;
    const int n0 = nt * 32;
    const int t = threadIdx.x;
    const int lane = t & 63, w = t >> 6, l15 = lane & 15, quad = lane >> 4;

    __shared__ __attribute__((aligned(16))) ushort As[32 * 40];
    __shared__ __attribute__((aligned(16))) ushort Bs[256 * 40];

    floatx4 acc[2][4];
#pragma unroll
    for (int i = 0; i < 2; i++)
#pragma unroll
        for (int j = 0; j < 4; j++) acc[i][j] = (floatx4)(0.0f);

    const float* xb = x + b * (CH * NN) + n0;

    for (int c0 = 0; c0 < CH; c0 += 32) {
        {
            int n = t & 31, g = t >> 5;
            short4v v;
#pragma unroll
            for (int i = 0; i < 4; i++)
                v[i] = (short)f2bf(xb[(c0 + g * 4 + i) * NN + n]);
            *(short4v*)&As[n * 40 + g * 4] = v;
        }
#pragma unroll
        for (int rep = 0; rep < 16; rep++) {
            int idx = rep * 256 + t;
            int row = idx >> 4, cp = idx & 15;
            const float* wf = (row < 128) ? (wqk + row * CH) : (wv + (row - 128) * CH);
            uint pack = (uint)f2bf(wf[c0 + cp * 2]) | ((uint)f2bf(wf[c0 + cp * 2 + 1]) << 16);
            *(uint*)&Bs[row * 40 + cp * 2] = pack;
        }
        __syncthreads();
        short8 a0 = *(short8*)&As[(l15) * 40 + quad * 8];
        short8 a1 = *(short8*)&As[(16 + l15) * 40 + quad * 8];
#pragma unroll
        for (int dt2 = 0; dt2 < 4; dt2++) {
            short8 bf = *(short8*)&Bs[(w * 64 + dt2 * 16 + l15) * 40 + quad * 8];
            acc[0][dt2] = __builtin_amdgcn_mfma_f32_16x16x32_bf16(a0, bf, acc[0][dt2], 0, 0, 0);
            acc[1][dt2] = __builtin_amdgcn_mfma_f32_16x16x32_bf16(a1, bf, acc[1][dt2], 0, 0, 0);
        }
        __syncthreads();
    }
#pragma unroll
    for (int ns = 0; ns < 2; ns++)
#pragma unroll
        for (int dt2 = 0; dt2 < 4; dt2++) {
            int ds_ = w * 64 + dt2 * 16 + l15;
#pragma unroll
            for (int r = 0; r < 4; r++) {
                int n = n0 + ns * 16 + quad * 4 + r;
                float val = acc[ns][dt2][r];
                if (ds_ < 128) {
                    Q[b * (NN * DD) + n * DD + ds_] = f2bf(val);
                } else {
                    int dv = ds_ - 128;
                    V[b * (NN * DD) + n * DD + dv] = f2bf(val + bv[dv]);
                }
            }
        }
}

__global__ __launch_bounds__(256) void k2_norm(
    const ushort* __restrict__ Q, ushort* __restrict__ V)
{
    const int ntile = blockIdx.x;
    const int b = blockIdx.y;
    const int n0 = ntile * 64;
    const int t = threadIdx.x;
    const int lane = t & 63, w = t >> 6, l15 = lane & 15, quad = lane >> 4;

    __shared__ __attribute__((aligned(16))) ushort Qs[64 * 136];
    __shared__ __attribute__((aligned(16))) ushort Qm2[64 * 136];

    const ushort* Qb = Q + b * (NN * DD);

#pragma unroll
    for (int rep = 0; rep < 16; rep++) {
        int idx = rep * 256 + t;
        int row = idx >> 6, dp = idx & 63;
        *(uint*)&Qs[row * 136 + dp * 2] = *(const uint*)&Qb[(n0 + row) * DD + dp * 2];
    }
    __syncthreads();

    short8 afr[4];
#pragma unroll
    for (int kd = 0; kd < 4; kd++)
        afr[kd] = *(short8*)&Qs[(w * 16 + l15) * 136 + kd * 32 + quad * 8];

    float sums[4] = {0.f, 0.f, 0.f, 0.f};

    for (int m0 = 0; m0 < NN; m0 += 64) {
#pragma unroll
        for (int rep = 0; rep < 16; rep++) {
            int idx = rep * 256 + t;
            int row = idx >> 6, dp = idx & 63;
            *(uint*)&Qm2[row * 136 + dp * 2] = *(const uint*)&Qb[(m0 + row) * DD + dp * 2];
        }
        __syncthreads();
#pragma unroll
        for (int ct = 0; ct < 4; ct++) {
            floatx4 s = (floatx4)(0.0f);
#pragma unroll
            for (int kd = 0; kd < 4; kd++) {
                short8 bf = *(short8*)&Qm2[(ct * 16 + l15) * 136 + kd * 32 + quad * 8];
                s = __builtin_amdgcn_mfma_f32_16x16x32_bf16(afr[kd], bf, s, 0, 0, 0);
            }
#pragma unroll
            for (int r = 0; r < 4; r++)
                sums[r] += __expf(s[r] * RSCALE);
        }
        __syncthreads();
    }

#pragma unroll
    for (int r = 0; r < 4; r++) {
        float s = sums[r];
        s += __shfl_xor(s, 1);
        s += __shfl_xor(s, 2);
        s += __shfl_xor(s, 4);
        s += __shfl_xor(s, 8);
        sums[r] = s;
    }

    ushort* Vb = V + b * (NN * DD);
#pragma unroll
    for (int r = 0; r < 4; r++) {
        int n = n0 + w * 16 + quad * 4 + r;
        float inv = 1.0f / sums[r];
        short8 vv = *(short8*)&Vb[n * DD + l15 * 8];
        short8 o;
#pragma unroll
        for (int i = 0; i < 8; i++)
            o[i] = (short)f2bf(bf2f((ushort)vv[i]) * inv);
        *(short8*)&Vb[n * DD + l15 * 8] = o;
    }
}

__global__ __launch_bounds__(256) void k3_attn(
    const ushort* __restrict__ Q, const ushort* __restrict__ Vp,
    float* __restrict__ out)
{
    const int mtile = blockIdx.x;
    const int b = blockIdx.y;
    const int m0 = mtile * 64;
    const int t = threadIdx.x;
    const int lane = t & 63, w = t >> 6, l15 = lane & 15, quad = lane >> 4;

    __shared__ __attribute__((aligned(16))) ushort Qs[64 * 136];
    __shared__ __attribute__((aligned(16))) ushort Qn2[32 * 136];
    __shared__ __attribute__((aligned(16))) ushort Vs2[128 * 40];
    __shared__ __attribute__((aligned(16))) ushort Ps2[64 * 40];

    const ushort* Qb = Q + b * (NN * DD);
    const ushort* Vpb = Vp + b * (NN * DD);

#pragma unroll
    for (int rep = 0; rep < 16; rep++) {
        int idx = rep * 256 + t;
        int row = idx >> 6, dp = idx & 63;
        *(uint*)&Qs[row * 136 + dp * 2] = *(const uint*)&Qb[(m0 + row) * DD + dp * 2];
    }
    __syncthreads();

    short8 afr[4];
#pragma unroll
    for (int kd = 0; kd < 4; kd++)
        afr[kd] = *(short8*)&Qs[(w * 16 + l15) * 136 + kd * 32 + quad * 8];

    floatx4 acc[2][4];
#pragma unroll
    for (int s = 0; s < 2; s++)
#pragma unroll
        for (int mt = 0; mt < 4; mt++) acc[s][mt] = (floatx4)(0.0f);

    for (int n0c = 0; n0c < NN; n0c += 32) {
#pragma unroll
        for (int rep = 0; rep < 8; rep++) {
            int idx = rep * 256 + t;
            int row = idx >> 6, dp = idx & 63;
            *(uint*)&Qn2[row * 136 + dp * 2] = *(const uint*)&Qb[(n0c + row) * DD + dp * 2];
        }
#pragma unroll
        for (int rep = 0; rep < 8; rep++) {
            int idx = rep * 256 + t;
            int np = idx >> 7, d = idx & 127;
            uint v0 = Vpb[(n0c + np * 2) * DD + d];
            uint v1 = Vpb[(n0c + np * 2 + 1) * DD + d];
            *(uint*)&Vs2[d * 40 + np * 2] = v0 | (v1 << 16);
        }
        __syncthreads();

#pragma unroll
        for (int nt2 = 0; nt2 < 2; nt2++) {
            floatx4 s = (floatx4)(0.0f);
#pragma unroll
            for (int kd = 0; kd < 4; kd++) {
                short8 bf = *(short8*)&Qn2[(nt2 * 16 + l15) * 136 + kd * 32 + quad * 8];
                s = __builtin_amdgcn_mfma_f32_16x16x32_bf16(afr[kd], bf, s, 0, 0, 0);
            }
#pragma unroll
            for (int r = 0; r < 4; r++) {
                float p = __expf(s[r] * RSCALE);
                Ps2[(w * 16 + quad * 4 + r) * 40 + nt2 * 16 + l15] = f2bf(p);
            }
        }
        __syncthreads();

        short8 pb[4];
#pragma unroll
        for (int mt = 0; mt < 4; mt++)
            pb[mt] = *(short8*)&Ps2[(mt * 16 + l15) * 40 + quad * 8];
#pragma unroll
        for (int sub = 0; sub < 2; sub++) {
            short8 va = *(short8*)&Vs2[(w * 32 + sub * 16 + l15) * 40 + quad * 8];
#pragma unroll
            for (int mt = 0; mt < 4; mt++)
                acc[sub][mt] = __builtin_amdgcn_mfma_f32_16x16x32_bf16(va, pb[mt], acc[sub][mt], 0, 0, 0);
        }
        __syncthreads();
    }

    float* ob = out + (size_t)b * DD * NN;
#pragma unroll
    for (int sub = 0; sub < 2; sub++)
#pragma unroll
        for (int mt = 0; mt < 4; mt++)
#pragma unroll
            for (int r = 0; r < 4; r++) {
                int d = w * 32 + sub * 16 + quad * 4 + r;
                int m = m0 + mt * 16 + l15;
                ob[(size_t)d * NN + m] = acc[sub][mt][r];
            }
}

extern "C" void kernel_launch(void* const* d_in, const int* in_sizes, int n_in,
                              void* d_out, int out_size, void* d_ws, size_t ws_size,
                              hipStream_t stream) {
    const float* x   = (const float*)d_in[0];
    const float* wqk = (const float*)d_in[1];
    const float* wv  = (const float*)d_in[2];
    const float* bv  = (const float*)d_in[3];
    float* out = (float*)d_out;

    // ws: Q [0,4M) | VT [4M,8M) | Wbf @8M (256K) | lsum @8M+256K (64K)
    //   | part @16M (16M)  -> 32 MiB total
    ushort* Q = (ushort*)d_ws;

    if (ws_size >= (size_t)33 * 1024 * 1024) {
        ushort* VT   = (ushort*)((char*)d_ws + (4u << 20));
        ushort* Wbf  = (ushort*)((char*)d_ws + (8u << 20));
        float*  lsum = (float*)((char*)d_ws + (8u << 20) + (256u << 10));
        float*  part = (float*)((char*)d_ws + (16u << 20));

        k0_prep<<<128, 256, 0, stream>>>(wqk, wv, Wbf, lsum);
        k1_proj<<<dim3(64, 8), 256, 0, stream>>>(x, Wbf, bv, Q, VT);
        kl_sum<<<dim3(136, 8), 256, 0, stream>>>(Q, lsum);
        k_fused<<<dim3(32, 2, 8), 256, 0, stream>>>(Q, VT, lsum, part);
        k_reduce<<<2048, 256, 0, stream>>>(part, out);
    } else {
        ushort* V = (ushort*)((char*)d_ws + (4u << 20));
        k1_fb<<<dim3(64, 8), 256, 0, stream>>>(x, wqk, wv, bv, Q, V);
        k2_norm<<<dim3(32, 8), 256, 0, stream>>>(Q, V);
        k3_attn<<<dim3(32, 8), 256, 0, stream>>>(Q, V, out);
    }
}